// Round 1
// baseline (3453.101 us; speedup 1.0000x reference)
//
#include <hip/hip_runtime.h>

#define N_NODES 20000
#define N_EDGES 320000
#define NGRAPH  256
#define NTAC    1000
#define IN_D    96
#define HD      512

// ---------------- transpose: in[R,C] -> out[C,R] ----------------
__global__ void k_transpose(const float* __restrict__ in, float* __restrict__ out,
                            int R, int C) {
  int idx = blockIdx.x * 256 + threadIdx.x;
  if (idx < R * C) {
    int r = idx / C, c = idx - r * C;
    out[c * R + r] = in[idx];
  }
}

// ---------------- embedding concat + graph node counts ----------------
__global__ void k_embed(const int* __restrict__ ntype, const int* __restrict__ ntac,
                        const int* __restrict__ batch,
                        const float* __restrict__ temb, const float* __restrict__ tacemb,
                        float* __restrict__ x, float* __restrict__ gcnt) {
  int tid = blockIdx.x * 256 + threadIdx.x;
  int node = tid / 24;
  int j = tid - node * 24;
  if (node >= N_NODES) return;
  float4 v;
  if (j < 8) {
    int t = ntype[node];
    v = *reinterpret_cast<const float4*>(&temb[t * 32 + j * 4]);
  } else {
    int s = ntac[node] + 1;
    s = s < 0 ? 0 : (s > NTAC ? NTAC : s);
    v = *reinterpret_cast<const float4*>(&tacemb[s * 64 + (j - 8) * 4]);
  }
  *reinterpret_cast<float4*>(&x[node * IN_D + j * 4]) = v;
  if (j == 0) atomicAdd(&gcnt[batch[node]], 1.0f);
}

// ---------------- in-degree ----------------
__global__ void k_degree(const int* __restrict__ dst, float* __restrict__ cnt) {
  int e = blockIdx.x * 256 + threadIdx.x;
  if (e < N_EDGES) atomicAdd(&cnt[dst[e]], 1.0f);
}

// ---------------- edge scatter-add, D=96 ----------------
__global__ void k_agg96(const int* __restrict__ src, const int* __restrict__ dst,
                        const float* __restrict__ x, float* __restrict__ agg) {
  int tid = blockIdx.x * 256 + threadIdx.x;
  int e = tid / 24;
  int j = tid - e * 24;
  if (e >= N_EDGES) return;
  int s = src[e], d = dst[e];
  float4 v = *reinterpret_cast<const float4*>(&x[s * IN_D + j * 4]);
  float* p = &agg[d * IN_D + j * 4];
  atomicAdd(p + 0, v.x); atomicAdd(p + 1, v.y);
  atomicAdd(p + 2, v.z); atomicAdd(p + 3, v.w);
}

// ---------------- edge scatter-add, D=512 ----------------
__global__ void k_agg512(const int* __restrict__ src, const int* __restrict__ dst,
                         const float* __restrict__ x1, float* __restrict__ agg) {
  int tid = blockIdx.x * 256 + threadIdx.x;
  int e = tid >> 7;
  int j = (tid & 127) << 2;
  if (e >= N_EDGES) return;
  int s = src[e], d = dst[e];
  float4 v = *reinterpret_cast<const float4*>(&x1[s * HD + j]);
  float* p = &agg[d * HD + j];
  atomicAdd(p + 0, v.x); atomicAdd(p + 1, v.y);
  atomicAdd(p + 2, v.z); atomicAdd(p + 3, v.w);
}

// ---------------- layer 1: x1 = relu(mean_agg @ W1l^T + b1l + x @ W1r^T) ----------------
__global__ __launch_bounds__(256) void k_layer1(
    const float* __restrict__ x, const float* __restrict__ agg,
    const float* __restrict__ cnt,
    const float* __restrict__ WlT, const float* __restrict__ bl,
    const float* __restrict__ WrT,
    float* __restrict__ x1) {
  __shared__ float xs[16][IN_D];
  __shared__ float as[16][IN_D];
  const int t = threadIdx.x;
  const int n0 = blockIdx.x * 16;
  for (int f = t; f < 16 * IN_D; f += 256) {
    int r = f / IN_D, c = f - r * IN_D;
    int node = n0 + r;
    xs[r][c] = x[node * IN_D + c];
    as[r][c] = agg[node * IN_D + c] * (1.0f / fmaxf(cnt[node], 1.0f));
  }
  __syncthreads();
  const int lane = t & 63;
  const int nb = (t >> 6) * 4;
  const int c0 = lane * 8;
  float acc[4][8];
#pragma unroll
  for (int n = 0; n < 4; ++n)
#pragma unroll
    for (int j = 0; j < 8; ++j) acc[n][j] = 0.0f;

#pragma unroll 2
  for (int k = 0; k < IN_D; ++k) {
    const float4 wl0 = *reinterpret_cast<const float4*>(&WlT[k * HD + c0]);
    const float4 wl1 = *reinterpret_cast<const float4*>(&WlT[k * HD + c0 + 4]);
    const float4 wr0 = *reinterpret_cast<const float4*>(&WrT[k * HD + c0]);
    const float4 wr1 = *reinterpret_cast<const float4*>(&WrT[k * HD + c0 + 4]);
#pragma unroll
    for (int n = 0; n < 4; ++n) {
      const float a  = as[nb + n][k];
      const float xv = xs[nb + n][k];
      acc[n][0] = fmaf(wl0.x, a, fmaf(wr0.x, xv, acc[n][0]));
      acc[n][1] = fmaf(wl0.y, a, fmaf(wr0.y, xv, acc[n][1]));
      acc[n][2] = fmaf(wl0.z, a, fmaf(wr0.z, xv, acc[n][2]));
      acc[n][3] = fmaf(wl0.w, a, fmaf(wr0.w, xv, acc[n][3]));
      acc[n][4] = fmaf(wl1.x, a, fmaf(wr1.x, xv, acc[n][4]));
      acc[n][5] = fmaf(wl1.y, a, fmaf(wr1.y, xv, acc[n][5]));
      acc[n][6] = fmaf(wl1.z, a, fmaf(wr1.z, xv, acc[n][6]));
      acc[n][7] = fmaf(wl1.w, a, fmaf(wr1.w, xv, acc[n][7]));
    }
  }
  const float4 b0 = *reinterpret_cast<const float4*>(&bl[c0]);
  const float4 b1 = *reinterpret_cast<const float4*>(&bl[c0 + 4]);
#pragma unroll
  for (int n = 0; n < 4; ++n) {
    const int node = n0 + nb + n;
    float4 o0, o1;
    o0.x = fmaxf(acc[n][0] + b0.x, 0.0f);
    o0.y = fmaxf(acc[n][1] + b0.y, 0.0f);
    o0.z = fmaxf(acc[n][2] + b0.z, 0.0f);
    o0.w = fmaxf(acc[n][3] + b0.w, 0.0f);
    o1.x = fmaxf(acc[n][4] + b1.x, 0.0f);
    o1.y = fmaxf(acc[n][5] + b1.y, 0.0f);
    o1.z = fmaxf(acc[n][6] + b1.z, 0.0f);
    o1.w = fmaxf(acc[n][7] + b1.w, 0.0f);
    *reinterpret_cast<float4*>(&x1[node * HD + c0])     = o0;
    *reinterpret_cast<float4*>(&x1[node * HD + c0 + 4]) = o1;
  }
}

// ---------------- layer 2: x2 = mean_agg @ W2l^T + b2l + x1 @ W2r^T; pool into gsum ----------------
__global__ __launch_bounds__(256) void k_layer2(
    const float* __restrict__ x1, const float* __restrict__ agg,
    const float* __restrict__ cnt, const int* __restrict__ batch,
    const float* __restrict__ WlT, const float* __restrict__ bl,
    const float* __restrict__ WrT,
    float* __restrict__ gsum) {
  __shared__ float xs[16][HD];
  __shared__ float as[16][HD];   // 64 KB total
  const int t = threadIdx.x;
  const int n0 = blockIdx.x * 16;
  for (int f = t; f < 16 * HD / 4; f += 256) {
    int r = f >> 7, c = (f & 127) << 2;
    int node = n0 + r;
    float inv = 1.0f / fmaxf(cnt[node], 1.0f);
    float4 xv = *reinterpret_cast<const float4*>(&x1[node * HD + c]);
    float4 av = *reinterpret_cast<const float4*>(&agg[node * HD + c]);
    av.x *= inv; av.y *= inv; av.z *= inv; av.w *= inv;
    *reinterpret_cast<float4*>(&xs[r][c]) = xv;
    *reinterpret_cast<float4*>(&as[r][c]) = av;
  }
  __syncthreads();
  const int lane = t & 63;
  const int nb = (t >> 6) * 4;
  const int c0 = lane * 8;
  float acc[4][8];
#pragma unroll
  for (int n = 0; n < 4; ++n)
#pragma unroll
    for (int j = 0; j < 8; ++j) acc[n][j] = 0.0f;

#pragma unroll 2
  for (int k = 0; k < HD; ++k) {
    const float4 wl0 = *reinterpret_cast<const float4*>(&WlT[k * HD + c0]);
    const float4 wl1 = *reinterpret_cast<const float4*>(&WlT[k * HD + c0 + 4]);
    const float4 wr0 = *reinterpret_cast<const float4*>(&WrT[k * HD + c0]);
    const float4 wr1 = *reinterpret_cast<const float4*>(&WrT[k * HD + c0 + 4]);
#pragma unroll
    for (int n = 0; n < 4; ++n) {
      const float a  = as[nb + n][k];
      const float xv = xs[nb + n][k];
      acc[n][0] = fmaf(wl0.x, a, fmaf(wr0.x, xv, acc[n][0]));
      acc[n][1] = fmaf(wl0.y, a, fmaf(wr0.y, xv, acc[n][1]));
      acc[n][2] = fmaf(wl0.z, a, fmaf(wr0.z, xv, acc[n][2]));
      acc[n][3] = fmaf(wl0.w, a, fmaf(wr0.w, xv, acc[n][3]));
      acc[n][4] = fmaf(wl1.x, a, fmaf(wr1.x, xv, acc[n][4]));
      acc[n][5] = fmaf(wl1.y, a, fmaf(wr1.y, xv, acc[n][5]));
      acc[n][6] = fmaf(wl1.z, a, fmaf(wr1.z, xv, acc[n][6]));
      acc[n][7] = fmaf(wl1.w, a, fmaf(wr1.w, xv, acc[n][7]));
    }
  }
  const float4 b0 = *reinterpret_cast<const float4*>(&bl[c0]);
  const float4 b1 = *reinterpret_cast<const float4*>(&bl[c0 + 4]);
#pragma unroll
  for (int n = 0; n < 4; ++n) {
    const int g = batch[n0 + nb + n];
    float* gp = &gsum[g * HD];
    atomicAdd(gp + c0 + 0, acc[n][0] + b0.x);
    atomicAdd(gp + c0 + 1, acc[n][1] + b0.y);
    atomicAdd(gp + c0 + 2, acc[n][2] + b0.z);
    atomicAdd(gp + c0 + 3, acc[n][3] + b0.w);
    atomicAdd(gp + c0 + 4, acc[n][4] + b1.x);
    atomicAdd(gp + c0 + 5, acc[n][5] + b1.y);
    atomicAdd(gp + c0 + 6, acc[n][6] + b1.z);
    atomicAdd(gp + c0 + 7, acc[n][7] + b1.w);
  }
}

// ---------------- classifier: 4 graphs / block ----------------
__global__ __launch_bounds__(256) void k_classifier(
    const float* __restrict__ gsum, const float* __restrict__ gcnt,
    const float* __restrict__ Wc1T, const float* __restrict__ bc1,
    const float* __restrict__ Wc2T, const float* __restrict__ bc2,
    float* __restrict__ out) {
  __shared__ float gr[4][HD];
  __shared__ float hs[4][HD];
  const int t = threadIdx.x;
  const int g0 = blockIdx.x * 4;
  for (int f = t; f < 4 * HD; f += 256) {
    int r = f >> 9, c = f & 511;
    gr[r][c] = gsum[(g0 + r) * HD + c] * (1.0f / fmaxf(gcnt[g0 + r], 1.0f));
  }
  __syncthreads();
  // phase A: h = relu(gr @ Wc1^T + bc1); wave w -> graph w
  const int w = t >> 6, lane = t & 63, c0 = lane * 8;
  {
    float acc[8];
#pragma unroll
    for (int j = 0; j < 8; ++j) acc[j] = 0.0f;
#pragma unroll 2
    for (int k = 0; k < HD; ++k) {
      const float4 w0 = *reinterpret_cast<const float4*>(&Wc1T[k * HD + c0]);
      const float4 w1 = *reinterpret_cast<const float4*>(&Wc1T[k * HD + c0 + 4]);
      const float g = gr[w][k];
      acc[0] = fmaf(w0.x, g, acc[0]); acc[1] = fmaf(w0.y, g, acc[1]);
      acc[2] = fmaf(w0.z, g, acc[2]); acc[3] = fmaf(w0.w, g, acc[3]);
      acc[4] = fmaf(w1.x, g, acc[4]); acc[5] = fmaf(w1.y, g, acc[5]);
      acc[6] = fmaf(w1.z, g, acc[6]); acc[7] = fmaf(w1.w, g, acc[7]);
    }
#pragma unroll
    for (int j = 0; j < 8; ++j)
      hs[w][c0 + j] = fmaxf(acc[j] + bc1[c0 + j], 0.0f);
  }
  __syncthreads();
  // phase B: logits = h @ Wc2^T + bc2
  for (int ci = 0; ci < 4; ++ci) {
    int c = t + ci * 256;
    if (c < NTAC) {
      float a0 = 0.f, a1 = 0.f, a2 = 0.f, a3 = 0.f;
      for (int k = 0; k < HD; ++k) {
        const float wv = Wc2T[k * NTAC + c];
        a0 = fmaf(hs[0][k], wv, a0);
        a1 = fmaf(hs[1][k], wv, a1);
        a2 = fmaf(hs[2][k], wv, a2);
        a3 = fmaf(hs[3][k], wv, a3);
      }
      const float b = bc2[c];
      out[(g0 + 0) * NTAC + c] = a0 + b;
      out[(g0 + 1) * NTAC + c] = a1 + b;
      out[(g0 + 2) * NTAC + c] = a2 + b;
      out[(g0 + 3) * NTAC + c] = a3 + b;
    }
  }
}

extern "C" void kernel_launch(void* const* d_in, const int* in_sizes, int n_in,
                              void* d_out, int out_size, void* d_ws, size_t ws_size,
                              hipStream_t stream) {
  const int*   node_type = (const int*)d_in[0];
  const int*   node_tac  = (const int*)d_in[1];
  const int*   edge      = (const int*)d_in[2];
  const int*   batch     = (const int*)d_in[3];
  const float* temb      = (const float*)d_in[4];
  const float* tacemb    = (const float*)d_in[5];
  const float* W1l       = (const float*)d_in[6];
  const float* b1l       = (const float*)d_in[7];
  const float* W1r       = (const float*)d_in[8];
  const float* W2l       = (const float*)d_in[9];
  const float* b2l       = (const float*)d_in[10];
  const float* W2r       = (const float*)d_in[11];
  const float* Wc1       = (const float*)d_in[12];
  const float* bc1       = (const float*)d_in[13];
  const float* Wc2       = (const float*)d_in[14];
  const float* bc2       = (const float*)d_in[15];
  const int* src = edge;
  const int* dst = edge + N_EDGES;

  float* ws = (float*)d_ws;
  size_t off = 0;
  float* AGG1 = ws + off; off += (size_t)N_NODES * IN_D;
  float* AGG2 = ws + off; off += (size_t)N_NODES * HD;
  float* CNT  = ws + off; off += N_NODES;
  float* GSUM = ws + off; off += NGRAPH * HD;
  float* GCNT = ws + off; off += NGRAPH;
  size_t zero_floats = off;
  float* X    = ws + off; off += (size_t)N_NODES * IN_D;
  float* X1   = ws + off; off += (size_t)N_NODES * HD;
  float* W1LT = ws + off; off += IN_D * HD;
  float* W1RT = ws + off; off += IN_D * HD;
  float* W2LT = ws + off; off += HD * HD;
  float* W2RT = ws + off; off += HD * HD;
  float* WC1T = ws + off; off += HD * HD;
  float* WC2T = ws + off; off += HD * NTAC;

  hipMemsetAsync(d_ws, 0, zero_floats * sizeof(float), stream);

  k_transpose<<<(HD * IN_D + 255) / 256, 256, 0, stream>>>(W1l, W1LT, HD, IN_D);
  k_transpose<<<(HD * IN_D + 255) / 256, 256, 0, stream>>>(W1r, W1RT, HD, IN_D);
  k_transpose<<<(HD * HD + 255) / 256, 256, 0, stream>>>(W2l, W2LT, HD, HD);
  k_transpose<<<(HD * HD + 255) / 256, 256, 0, stream>>>(W2r, W2RT, HD, HD);
  k_transpose<<<(HD * HD + 255) / 256, 256, 0, stream>>>(Wc1, WC1T, HD, HD);
  k_transpose<<<(NTAC * HD + 255) / 256, 256, 0, stream>>>(Wc2, WC2T, NTAC, HD);

  k_embed<<<(N_NODES * 24) / 256, 256, 0, stream>>>(node_type, node_tac, batch,
                                                    temb, tacemb, X, GCNT);
  k_degree<<<N_EDGES / 256, 256, 0, stream>>>(dst, CNT);
  k_agg96<<<(N_EDGES * 24) / 256, 256, 0, stream>>>(src, dst, X, AGG1);
  k_layer1<<<N_NODES / 16, 256, 0, stream>>>(X, AGG1, CNT, W1LT, b1l, W1RT, X1);
  k_agg512<<<(N_EDGES / 2), 256, 0, stream>>>(src, dst, X1, AGG2);  // E*128/256
  k_layer2<<<N_NODES / 16, 256, 0, stream>>>(X1, AGG2, CNT, batch, W2LT, b2l, W2RT, GSUM);
  k_classifier<<<NGRAPH / 4, 256, 0, stream>>>(GSUM, GCNT, WC1T, bc1, WC2T, bc2,
                                               (float*)d_out);
}

// Round 2
// 1084.415 us; speedup vs baseline: 3.1843x; 3.1843x over previous
//
#include <hip/hip_runtime.h>

#define N_NODES 20000
#define N_EDGES 320000
#define NGRAPH  256
#define NTAC    1000
#define IN_D    96
#define HD      512

// ---------------- transpose: in[R,C] -> out[C,R] ----------------
__global__ void k_transpose(const float* __restrict__ in, float* __restrict__ out,
                            int R, int C) {
  int idx = blockIdx.x * 256 + threadIdx.x;
  if (idx < R * C) {
    int r = idx / C, c = idx - r * C;
    out[c * R + r] = in[idx];
  }
}

// ---------------- embedding concat + graph node counts ----------------
__global__ void k_embed(const int* __restrict__ ntype, const int* __restrict__ ntac,
                        const int* __restrict__ batch,
                        const float* __restrict__ temb, const float* __restrict__ tacemb,
                        float* __restrict__ x, float* __restrict__ gcnt) {
  int tid = blockIdx.x * 256 + threadIdx.x;
  int node = tid / 24;
  int j = tid - node * 24;
  if (node >= N_NODES) return;
  float4 v;
  if (j < 8) {
    int t = ntype[node];
    v = *reinterpret_cast<const float4*>(&temb[t * 32 + j * 4]);
  } else {
    int s = ntac[node] + 1;
    s = s < 0 ? 0 : (s > NTAC ? NTAC : s);
    v = *reinterpret_cast<const float4*>(&tacemb[s * 64 + (j - 8) * 4]);
  }
  *reinterpret_cast<float4*>(&x[node * IN_D + j * 4]) = v;
  if (j == 0) atomicAdd(&gcnt[batch[node]], 1.0f);
}

// ---------------- CSR build: degree histogram ----------------
__global__ void k_degree(const int* __restrict__ dst, int* __restrict__ deg) {
  int e = blockIdx.x * 256 + threadIdx.x;
  if (e < N_EDGES) atomicAdd(&deg[dst[e]], 1);
}

// ---------------- CSR build: exclusive scan over N_NODES degrees ----------------
__global__ __launch_bounds__(1024) void k_scan(const int* __restrict__ deg,
                                               int* __restrict__ rowstart) {
  __shared__ int partial[1024];
  const int t = threadIdx.x;
  const int CH = (N_NODES + 1023) / 1024;  // 20
  int s = 0;
  for (int i = 0; i < CH; ++i) {
    int idx = t * CH + i;
    if (idx < N_NODES) s += deg[idx];
  }
  partial[t] = s;
  __syncthreads();
  for (int off = 1; off < 1024; off <<= 1) {
    int v = (t >= off) ? partial[t - off] : 0;
    __syncthreads();
    partial[t] += v;
    __syncthreads();
  }
  int run = (t == 0) ? 0 : partial[t - 1];
  for (int i = 0; i < CH; ++i) {
    int idx = t * CH + i;
    if (idx < N_NODES) { rowstart[idx] = run; run += deg[idx]; }
  }
  if (t == 1023) rowstart[N_NODES] = run;
}

// ---------------- CSR build: scatter src ids into dst-sorted order ----------------
__global__ void k_scatter(const int* __restrict__ src, const int* __restrict__ dst,
                          const int* __restrict__ rowstart, int* __restrict__ cur,
                          int* __restrict__ esrc) {
  int e = blockIdx.x * 256 + threadIdx.x;
  if (e < N_EDGES) {
    int d = dst[e];
    int p = rowstart[d] + atomicAdd(&cur[d], 1);
    esrc[p] = src[e];
  }
}

// ---------------- gather-mean, D=96 (writes normalized agg) ----------------
__global__ __launch_bounds__(256) void k_gather96(
    const int* __restrict__ rowstart, const int* __restrict__ esrc,
    const float* __restrict__ x, float* __restrict__ agg) {
  int tid = blockIdx.x * 256 + threadIdx.x;
  int node = tid / 24;
  int c = (tid - node * 24) * 4;
  if (node >= N_NODES) return;
  const int s0 = rowstart[node], s1 = rowstart[node + 1];
  float4 acc = {0.f, 0.f, 0.f, 0.f};
  for (int i = s0; i < s1; ++i) {
    int nbr = esrc[i];
    float4 v = *reinterpret_cast<const float4*>(&x[nbr * IN_D + c]);
    acc.x += v.x; acc.y += v.y; acc.z += v.z; acc.w += v.w;
  }
  const float inv = 1.0f / fmaxf((float)(s1 - s0), 1.0f);
  acc.x *= inv; acc.y *= inv; acc.z *= inv; acc.w *= inv;
  *reinterpret_cast<float4*>(&agg[node * IN_D + c]) = acc;
}

// ---------------- gather-mean, D=512 (writes normalized agg) ----------------
__global__ __launch_bounds__(256) void k_gather512(
    const int* __restrict__ rowstart, const int* __restrict__ esrc,
    const float* __restrict__ x1, float* __restrict__ agg) {
  int tid = blockIdx.x * 256 + threadIdx.x;
  int node = tid >> 7;
  int c = (tid & 127) << 2;
  const int s0 = rowstart[node], s1 = rowstart[node + 1];
  float4 acc = {0.f, 0.f, 0.f, 0.f};
  for (int i = s0; i < s1; ++i) {
    int nbr = esrc[i];
    float4 v = *reinterpret_cast<const float4*>(&x1[nbr * HD + c]);
    acc.x += v.x; acc.y += v.y; acc.z += v.z; acc.w += v.w;
  }
  const float inv = 1.0f / fmaxf((float)(s1 - s0), 1.0f);
  acc.x *= inv; acc.y *= inv; acc.z *= inv; acc.w *= inv;
  *reinterpret_cast<float4*>(&agg[node * HD + c]) = acc;
}

// ---------------- layer 1: x1 = relu(agg @ W1l^T + b1l + x @ W1r^T) ----------------
__global__ __launch_bounds__(256) void k_layer1(
    const float* __restrict__ x, const float* __restrict__ agg,
    const float* __restrict__ WlT, const float* __restrict__ bl,
    const float* __restrict__ WrT,
    float* __restrict__ x1) {
  __shared__ float xs[16][IN_D];
  __shared__ float as[16][IN_D];
  const int t = threadIdx.x;
  const int n0 = blockIdx.x * 16;
  for (int f = t; f < 16 * IN_D; f += 256) {
    int r = f / IN_D, c = f - r * IN_D;
    int node = n0 + r;
    xs[r][c] = x[node * IN_D + c];
    as[r][c] = agg[node * IN_D + c];
  }
  __syncthreads();
  const int lane = t & 63;
  const int nb = (t >> 6) * 4;
  const int c0 = lane * 8;
  float acc[4][8];
#pragma unroll
  for (int n = 0; n < 4; ++n)
#pragma unroll
    for (int j = 0; j < 8; ++j) acc[n][j] = 0.0f;

#pragma unroll 2
  for (int k = 0; k < IN_D; ++k) {
    const float4 wl0 = *reinterpret_cast<const float4*>(&WlT[k * HD + c0]);
    const float4 wl1 = *reinterpret_cast<const float4*>(&WlT[k * HD + c0 + 4]);
    const float4 wr0 = *reinterpret_cast<const float4*>(&WrT[k * HD + c0]);
    const float4 wr1 = *reinterpret_cast<const float4*>(&WrT[k * HD + c0 + 4]);
#pragma unroll
    for (int n = 0; n < 4; ++n) {
      const float a  = as[nb + n][k];
      const float xv = xs[nb + n][k];
      acc[n][0] = fmaf(wl0.x, a, fmaf(wr0.x, xv, acc[n][0]));
      acc[n][1] = fmaf(wl0.y, a, fmaf(wr0.y, xv, acc[n][1]));
      acc[n][2] = fmaf(wl0.z, a, fmaf(wr0.z, xv, acc[n][2]));
      acc[n][3] = fmaf(wl0.w, a, fmaf(wr0.w, xv, acc[n][3]));
      acc[n][4] = fmaf(wl1.x, a, fmaf(wr1.x, xv, acc[n][4]));
      acc[n][5] = fmaf(wl1.y, a, fmaf(wr1.y, xv, acc[n][5]));
      acc[n][6] = fmaf(wl1.z, a, fmaf(wr1.z, xv, acc[n][6]));
      acc[n][7] = fmaf(wl1.w, a, fmaf(wr1.w, xv, acc[n][7]));
    }
  }
  const float4 b0 = *reinterpret_cast<const float4*>(&bl[c0]);
  const float4 b1 = *reinterpret_cast<const float4*>(&bl[c0 + 4]);
#pragma unroll
  for (int n = 0; n < 4; ++n) {
    const int node = n0 + nb + n;
    float4 o0, o1;
    o0.x = fmaxf(acc[n][0] + b0.x, 0.0f);
    o0.y = fmaxf(acc[n][1] + b0.y, 0.0f);
    o0.z = fmaxf(acc[n][2] + b0.z, 0.0f);
    o0.w = fmaxf(acc[n][3] + b0.w, 0.0f);
    o1.x = fmaxf(acc[n][4] + b1.x, 0.0f);
    o1.y = fmaxf(acc[n][5] + b1.y, 0.0f);
    o1.z = fmaxf(acc[n][6] + b1.z, 0.0f);
    o1.w = fmaxf(acc[n][7] + b1.w, 0.0f);
    *reinterpret_cast<float4*>(&x1[node * HD + c0])     = o0;
    *reinterpret_cast<float4*>(&x1[node * HD + c0 + 4]) = o1;
  }
}

// ---------------- layer 2: x2 = agg @ W2l^T + b2l + x1 @ W2r^T; pool into gsum ----------------
__global__ __launch_bounds__(256) void k_layer2(
    const float* __restrict__ x1, const float* __restrict__ agg,
    const int* __restrict__ batch,
    const float* __restrict__ WlT, const float* __restrict__ bl,
    const float* __restrict__ WrT,
    float* __restrict__ gsum) {
  __shared__ float xs[16][HD];
  __shared__ float as[16][HD];   // 64 KB total
  const int t = threadIdx.x;
  const int n0 = blockIdx.x * 16;
  for (int f = t; f < 16 * HD / 4; f += 256) {
    int r = f >> 7, c = (f & 127) << 2;
    int node = n0 + r;
    float4 xv = *reinterpret_cast<const float4*>(&x1[node * HD + c]);
    float4 av = *reinterpret_cast<const float4*>(&agg[node * HD + c]);
    *reinterpret_cast<float4*>(&xs[r][c]) = xv;
    *reinterpret_cast<float4*>(&as[r][c]) = av;
  }
  __syncthreads();
  const int lane = t & 63;
  const int nb = (t >> 6) * 4;
  const int c0 = lane * 8;
  float acc[4][8];
#pragma unroll
  for (int n = 0; n < 4; ++n)
#pragma unroll
    for (int j = 0; j < 8; ++j) acc[n][j] = 0.0f;

#pragma unroll 2
  for (int k = 0; k < HD; ++k) {
    const float4 wl0 = *reinterpret_cast<const float4*>(&WlT[k * HD + c0]);
    const float4 wl1 = *reinterpret_cast<const float4*>(&WlT[k * HD + c0 + 4]);
    const float4 wr0 = *reinterpret_cast<const float4*>(&WrT[k * HD + c0]);
    const float4 wr1 = *reinterpret_cast<const float4*>(&WrT[k * HD + c0 + 4]);
#pragma unroll
    for (int n = 0; n < 4; ++n) {
      const float a  = as[nb + n][k];
      const float xv = xs[nb + n][k];
      acc[n][0] = fmaf(wl0.x, a, fmaf(wr0.x, xv, acc[n][0]));
      acc[n][1] = fmaf(wl0.y, a, fmaf(wr0.y, xv, acc[n][1]));
      acc[n][2] = fmaf(wl0.z, a, fmaf(wr0.z, xv, acc[n][2]));
      acc[n][3] = fmaf(wl0.w, a, fmaf(wr0.w, xv, acc[n][3]));
      acc[n][4] = fmaf(wl1.x, a, fmaf(wr1.x, xv, acc[n][4]));
      acc[n][5] = fmaf(wl1.y, a, fmaf(wr1.y, xv, acc[n][5]));
      acc[n][6] = fmaf(wl1.z, a, fmaf(wr1.z, xv, acc[n][6]));
      acc[n][7] = fmaf(wl1.w, a, fmaf(wr1.w, xv, acc[n][7]));
    }
  }
  const float4 b0 = *reinterpret_cast<const float4*>(&bl[c0]);
  const float4 b1 = *reinterpret_cast<const float4*>(&bl[c0 + 4]);
#pragma unroll
  for (int n = 0; n < 4; ++n) {
    const int g = batch[n0 + nb + n];
    float* gp = &gsum[g * HD];
    atomicAdd(gp + c0 + 0, acc[n][0] + b0.x);
    atomicAdd(gp + c0 + 1, acc[n][1] + b0.y);
    atomicAdd(gp + c0 + 2, acc[n][2] + b0.z);
    atomicAdd(gp + c0 + 3, acc[n][3] + b0.w);
    atomicAdd(gp + c0 + 4, acc[n][4] + b1.x);
    atomicAdd(gp + c0 + 5, acc[n][5] + b1.y);
    atomicAdd(gp + c0 + 6, acc[n][6] + b1.z);
    atomicAdd(gp + c0 + 7, acc[n][7] + b1.w);
  }
}

// ---------------- classifier: 4 graphs / block ----------------
__global__ __launch_bounds__(256) void k_classifier(
    const float* __restrict__ gsum, const float* __restrict__ gcnt,
    const float* __restrict__ Wc1T, const float* __restrict__ bc1,
    const float* __restrict__ Wc2T, const float* __restrict__ bc2,
    float* __restrict__ out) {
  __shared__ float gr[4][HD];
  __shared__ float hs[4][HD];
  const int t = threadIdx.x;
  const int g0 = blockIdx.x * 4;
  for (int f = t; f < 4 * HD; f += 256) {
    int r = f >> 9, c = f & 511;
    gr[r][c] = gsum[(g0 + r) * HD + c] * (1.0f / fmaxf(gcnt[g0 + r], 1.0f));
  }
  __syncthreads();
  const int w = t >> 6, lane = t & 63, c0 = lane * 8;
  {
    float acc[8];
#pragma unroll
    for (int j = 0; j < 8; ++j) acc[j] = 0.0f;
#pragma unroll 2
    for (int k = 0; k < HD; ++k) {
      const float4 w0 = *reinterpret_cast<const float4*>(&Wc1T[k * HD + c0]);
      const float4 w1 = *reinterpret_cast<const float4*>(&Wc1T[k * HD + c0 + 4]);
      const float g = gr[w][k];
      acc[0] = fmaf(w0.x, g, acc[0]); acc[1] = fmaf(w0.y, g, acc[1]);
      acc[2] = fmaf(w0.z, g, acc[2]); acc[3] = fmaf(w0.w, g, acc[3]);
      acc[4] = fmaf(w1.x, g, acc[4]); acc[5] = fmaf(w1.y, g, acc[5]);
      acc[6] = fmaf(w1.z, g, acc[6]); acc[7] = fmaf(w1.w, g, acc[7]);
    }
#pragma unroll
    for (int j = 0; j < 8; ++j)
      hs[w][c0 + j] = fmaxf(acc[j] + bc1[c0 + j], 0.0f);
  }
  __syncthreads();
  for (int ci = 0; ci < 4; ++ci) {
    int c = t + ci * 256;
    if (c < NTAC) {
      float a0 = 0.f, a1 = 0.f, a2 = 0.f, a3 = 0.f;
      for (int k = 0; k < HD; ++k) {
        const float wv = Wc2T[k * NTAC + c];
        a0 = fmaf(hs[0][k], wv, a0);
        a1 = fmaf(hs[1][k], wv, a1);
        a2 = fmaf(hs[2][k], wv, a2);
        a3 = fmaf(hs[3][k], wv, a3);
      }
      const float b = bc2[c];
      out[(g0 + 0) * NTAC + c] = a0 + b;
      out[(g0 + 1) * NTAC + c] = a1 + b;
      out[(g0 + 2) * NTAC + c] = a2 + b;
      out[(g0 + 3) * NTAC + c] = a3 + b;
    }
  }
}

extern "C" void kernel_launch(void* const* d_in, const int* in_sizes, int n_in,
                              void* d_out, int out_size, void* d_ws, size_t ws_size,
                              hipStream_t stream) {
  const int*   node_type = (const int*)d_in[0];
  const int*   node_tac  = (const int*)d_in[1];
  const int*   edge      = (const int*)d_in[2];
  const int*   batch     = (const int*)d_in[3];
  const float* temb      = (const float*)d_in[4];
  const float* tacemb    = (const float*)d_in[5];
  const float* W1l       = (const float*)d_in[6];
  const float* b1l       = (const float*)d_in[7];
  const float* W1r       = (const float*)d_in[8];
  const float* W2l       = (const float*)d_in[9];
  const float* b2l       = (const float*)d_in[10];
  const float* W2r       = (const float*)d_in[11];
  const float* Wc1       = (const float*)d_in[12];
  const float* bc1       = (const float*)d_in[13];
  const float* Wc2       = (const float*)d_in[14];
  const float* bc2       = (const float*)d_in[15];
  const int* src = edge;
  const int* dst = edge + N_EDGES;

  // ---- workspace layout (elements are 4 B; float4 users are 16B-aligned) ----
  char* wsb = (char*)d_ws;
  int*   DEG  = (int*)wsb;                       // N            (zeroed)
  int*   CUR  = DEG + N_NODES;                   // N            (zeroed)
  float* GSUM = (float*)(CUR + N_NODES);         // G*H          (zeroed)
  float* GCNT = GSUM + NGRAPH * HD;              // G            (zeroed)
  size_t zero_bytes = (size_t)(2 * N_NODES + NGRAPH * HD + NGRAPH) * 4;
  int*   ROWS = (int*)(GCNT + NGRAPH);           // N+16 (padded for alignment)
  int*   ESRC = ROWS + (N_NODES + 16);           // E
  float* AGG1 = (float*)(ESRC + N_EDGES);        // N*96
  float* X    = AGG1 + (size_t)N_NODES * IN_D;   // N*96
  float* X1   = X    + (size_t)N_NODES * IN_D;   // N*H
  float* AGG2 = X1   + (size_t)N_NODES * HD;     // N*H
  float* W1LT = AGG2 + (size_t)N_NODES * HD;     // 96*512
  float* W1RT = W1LT + IN_D * HD;
  float* W2LT = W1RT + IN_D * HD;                // 512*512
  float* W2RT = W2LT + HD * HD;
  float* WC1T = W2RT + HD * HD;
  float* WC2T = WC1T + HD * HD;                  // 512*1000

  hipMemsetAsync(d_ws, 0, zero_bytes, stream);

  k_transpose<<<(HD * IN_D + 255) / 256, 256, 0, stream>>>(W1l, W1LT, HD, IN_D);
  k_transpose<<<(HD * IN_D + 255) / 256, 256, 0, stream>>>(W1r, W1RT, HD, IN_D);
  k_transpose<<<(HD * HD + 255) / 256, 256, 0, stream>>>(W2l, W2LT, HD, HD);
  k_transpose<<<(HD * HD + 255) / 256, 256, 0, stream>>>(W2r, W2RT, HD, HD);
  k_transpose<<<(HD * HD + 255) / 256, 256, 0, stream>>>(Wc1, WC1T, HD, HD);
  k_transpose<<<(NTAC * HD + 255) / 256, 256, 0, stream>>>(Wc2, WC2T, NTAC, HD);

  // CSR build
  k_degree<<<N_EDGES / 256, 256, 0, stream>>>(dst, DEG);
  k_scan<<<1, 1024, 0, stream>>>(DEG, ROWS);
  k_scatter<<<N_EDGES / 256, 256, 0, stream>>>(src, dst, ROWS, CUR, ESRC);

  k_embed<<<(N_NODES * 24) / 256, 256, 0, stream>>>(node_type, node_tac, batch,
                                                    temb, tacemb, X, GCNT);
  k_gather96<<<(N_NODES * 24) / 256, 256, 0, stream>>>(ROWS, ESRC, X, AGG1);
  k_layer1<<<N_NODES / 16, 256, 0, stream>>>(X, AGG1, W1LT, b1l, W1RT, X1);
  k_gather512<<<(N_NODES * 128) / 256, 256, 0, stream>>>(ROWS, ESRC, X1, AGG2);
  k_layer2<<<N_NODES / 16, 256, 0, stream>>>(X1, AGG2, batch, W2LT, b2l, W2RT, GSUM);
  k_classifier<<<NGRAPH / 4, 256, 0, stream>>>(GSUM, GCNT, WC1T, bc1, WC2T, bc2,
                                               (float*)d_out);
}

// Round 3
// 457.430 us; speedup vs baseline: 7.5489x; 2.3707x over previous
//
#include <hip/hip_runtime.h>

#define N_NODES 20000
#define N_EDGES 320000
#define NGRAPH  256
#define NTAC    1000
#define HD      512

typedef __attribute__((ext_vector_type(8))) short bf16x8;
typedef __attribute__((ext_vector_type(4))) short short4v;
typedef __attribute__((ext_vector_type(4))) float f32x4;

__device__ __forceinline__ short f2bf(float f) {      // RNE float->bf16
  union { float f; unsigned u; } v; v.f = f;
  unsigned r = v.u + 0x7FFFu + ((v.u >> 16) & 1u);
  return (short)(r >> 16);
}
__device__ __forceinline__ float bf2f(short s) {
  union { unsigned u; float f; } v;
  v.u = ((unsigned)(unsigned short)s) << 16;
  return v.f;
}
__device__ __forceinline__ void gload16(const void* g, void* l) {
  __builtin_amdgcn_global_load_lds((const __attribute__((address_space(1))) void*)g,
                                   (__attribute__((address_space(3))) void*)l,
                                   16, 0, 0);
}

// ---------------- transpose: in[R,C] -> out[C,R] (classifier weights, fp32) ----
__global__ void k_transpose(const float* __restrict__ in, float* __restrict__ out,
                            int R, int C) {
  int idx = blockIdx.x * 256 + threadIdx.x;
  if (idx < R * C) {
    int r = idx / C, c = idx - r * C;
    out[c * R + r] = in[idx];
  }
}

// ---------------- Bcat[n][Ktot] = [Wl[n][0:Kl] | Wr[n][0:Kl2]] fp32->bf16 ------
__global__ void k_bcat(const float* __restrict__ Wl, const float* __restrict__ Wr,
                       short* __restrict__ Bc, int Kl, int Ktot) {
  int tid = blockIdx.x * 256 + threadIdx.x;
  int kq = Ktot >> 2;
  int n = tid / kq, k4 = (tid - n * kq) << 2;
  if (n >= HD) return;
  const float* srcp = (k4 < Kl) ? &Wl[(size_t)n * Kl + k4]
                                : &Wr[(size_t)n * (Ktot - Kl) + (k4 - Kl)];
  float4 v = *reinterpret_cast<const float4*>(srcp);
  short4v o; o[0] = f2bf(v.x); o[1] = f2bf(v.y); o[2] = f2bf(v.z); o[3] = f2bf(v.w);
  *reinterpret_cast<short4v*>(&Bc[(size_t)n * Ktot + k4]) = o;
}

// ---------------- embedding concat -> bf16 into A1[:,96:192] -------------------
__global__ void k_embed(const int* __restrict__ ntype, const int* __restrict__ ntac,
                        const float* __restrict__ temb, const float* __restrict__ tacemb,
                        short* __restrict__ A1) {
  int tid = blockIdx.x * 256 + threadIdx.x;
  int node = tid / 24;
  int j = tid - node * 24;
  if (node >= N_NODES) return;
  float4 v;
  int col;
  if (j < 8) {
    int t = ntype[node];
    v = *reinterpret_cast<const float4*>(&temb[t * 32 + j * 4]);
    col = j * 4;
  } else {
    int s = ntac[node] + 1;
    s = s < 0 ? 0 : (s > NTAC ? NTAC : s);
    v = *reinterpret_cast<const float4*>(&tacemb[s * 64 + (j - 8) * 4]);
    col = 32 + (j - 8) * 4;
  }
  short4v o; o[0] = f2bf(v.x); o[1] = f2bf(v.y); o[2] = f2bf(v.z); o[3] = f2bf(v.w);
  *reinterpret_cast<short4v*>(&A1[(size_t)node * 192 + 96 + col]) = o;
}

// ---------------- CSR build ----------------
__global__ void k_degree(const int* __restrict__ dst, int* __restrict__ deg) {
  int e = blockIdx.x * 256 + threadIdx.x;
  if (e < N_EDGES) atomicAdd(&deg[dst[e]], 1);
}

__global__ __launch_bounds__(1024) void k_scan(const int* __restrict__ deg,
                                               int* __restrict__ rowstart) {
  __shared__ int partial[1024];
  const int t = threadIdx.x;
  const int CH = (N_NODES + 1023) / 1024;  // 20
  int s = 0;
  for (int i = 0; i < CH; ++i) {
    int idx = t * CH + i;
    if (idx < N_NODES) s += deg[idx];
  }
  partial[t] = s;
  __syncthreads();
  for (int off = 1; off < 1024; off <<= 1) {
    int v = (t >= off) ? partial[t - off] : 0;
    __syncthreads();
    partial[t] += v;
    __syncthreads();
  }
  int run = (t == 0) ? 0 : partial[t - 1];
  for (int i = 0; i < CH; ++i) {
    int idx = t * CH + i;
    if (idx < N_NODES) { rowstart[idx] = run; run += deg[idx]; }
  }
  if (t == 1023) rowstart[N_NODES] = run;
}

__global__ void k_scatter(const int* __restrict__ src, const int* __restrict__ dst,
                          const int* __restrict__ rowstart, int* __restrict__ cur,
                          int* __restrict__ esrc) {
  int e = blockIdx.x * 256 + threadIdx.x;
  if (e < N_EDGES) {
    int d = dst[e];
    int p = rowstart[d] + atomicAdd(&cur[d], 1);
    esrc[p] = src[e];
  }
}

// ---------------- graph row ranges (batch is sorted) ----------------
__global__ void k_gbounds(const int* __restrict__ batch, int* __restrict__ rstart) {
  int i = blockIdx.x * 256 + threadIdx.x;
  if (i >= N_NODES) return;
  int b = batch[i];
  int bp = (i == 0) ? -1 : batch[i - 1];
  for (int g = bp + 1; g <= b; ++g) rstart[g] = i;
  if (i == N_NODES - 1)
    for (int g = b + 1; g <= NGRAPH; ++g) rstart[g] = N_NODES;
}

// ---------------- gather-mean D=96: A1[:,0:96] = mean nbr A1[:,96:192] --------
__global__ __launch_bounds__(256) void k_gather96(
    const int* __restrict__ rowstart, const int* __restrict__ esrc,
    short* __restrict__ A1) {
  int tid = blockIdx.x * 256 + threadIdx.x;
  int node = tid / 24;
  int c = (tid - node * 24) * 4;
  if (node >= N_NODES) return;
  const int s0 = rowstart[node], s1 = rowstart[node + 1];
  float a0 = 0.f, a1 = 0.f, a2 = 0.f, a3 = 0.f;
  for (int i = s0; i < s1; ++i) {
    int nbr = esrc[i];
    short4v v = *reinterpret_cast<const short4v*>(&A1[(size_t)nbr * 192 + 96 + c]);
    a0 += bf2f(v[0]); a1 += bf2f(v[1]); a2 += bf2f(v[2]); a3 += bf2f(v[3]);
  }
  const float inv = 1.0f / fmaxf((float)(s1 - s0), 1.0f);
  short4v o; o[0] = f2bf(a0 * inv); o[1] = f2bf(a1 * inv);
  o[2] = f2bf(a2 * inv); o[3] = f2bf(a3 * inv);
  *reinterpret_cast<short4v*>(&A1[(size_t)node * 192 + c]) = o;
}

// ---------------- gather-mean D=512: A2[:,0:512] = mean nbr A2[:,512:1024] ----
__global__ __launch_bounds__(256) void k_gather512(
    const int* __restrict__ rowstart, const int* __restrict__ esrc,
    short* __restrict__ A2) {
  int tid = blockIdx.x * 256 + threadIdx.x;
  int node = tid >> 6;
  int c = (tid & 63) << 3;
  const int s0 = rowstart[node], s1 = rowstart[node + 1];
  float acc[8] = {0.f, 0.f, 0.f, 0.f, 0.f, 0.f, 0.f, 0.f};
  for (int i = s0; i < s1; ++i) {
    int nbr = esrc[i];
    bf16x8 v = *reinterpret_cast<const bf16x8*>(&A2[(size_t)nbr * 1024 + 512 + c]);
#pragma unroll
    for (int j = 0; j < 8; ++j) acc[j] += bf2f(v[j]);
  }
  const float inv = 1.0f / fmaxf((float)(s1 - s0), 1.0f);
  bf16x8 o;
#pragma unroll
  for (int j = 0; j < 8; ++j) o[j] = f2bf(acc[j] * inv);
  *reinterpret_cast<bf16x8*>(&A2[(size_t)node * 1024 + c]) = o;
}

// ---------------- bf16 MFMA GEMM: C[M,512] = A[M,K] @ B[512,K]^T + bias -------
// MODE 0: relu, store bf16 to outS[row*ostride + ooff + col] (layer1 -> A2 x1-half)
// MODE 1: store fp32 to outF[row*512 + col]                  (layer2 -> X2)
template<int K, int MODE>
__global__ __launch_bounds__(256) void k_gemm(
    const short* __restrict__ A, const short* __restrict__ B,
    const float* __restrict__ bias,
    short* __restrict__ outS, float* __restrict__ outF,
    int ostride, int ooff) {
  __shared__ short As[128 * 32];
  __shared__ short Bs[128 * 32];
  const int t = threadIdx.x;
  const int m0 = blockIdx.x * 128;
  const int n0 = blockIdx.y * 128;
  const int l = t & 63, wid = t >> 6;
  const int wr = (wid >> 1) * 64, wc = (wid & 1) * 64;
  const int fr = l & 15, fs = l >> 4;

  f32x4 acc[4][4];
#pragma unroll
  for (int a = 0; a < 4; ++a)
#pragma unroll
    for (int b = 0; b < 4; ++b) acc[a][b] = (f32x4){0.f, 0.f, 0.f, 0.f};

  // staging geometry (swizzled source -> linear LDS; idx = r*4 + phys_slot)
  const int idx0 = t, r0 = idx0 >> 2, sp0 = idx0 & 3;
  const int sl0 = (sp0 - (r0 >> 1)) & 3;
  const int idx1 = t + 256, r1 = idx1 >> 2, sp1 = idx1 & 3;
  const int sl1 = (sp1 - (r1 >> 1)) & 3;
  int rowA0 = m0 + r0; rowA0 = rowA0 < N_NODES ? rowA0 : N_NODES - 1;
  int rowA1 = m0 + r1; rowA1 = rowA1 < N_NODES ? rowA1 : N_NODES - 1;

  for (int k0 = 0; k0 < K; k0 += 32) {
    gload16(A + (size_t)rowA0 * K + k0 + sl0 * 8, &As[idx0 * 8]);
    gload16(B + (size_t)(n0 + r0) * K + k0 + sl0 * 8, &Bs[idx0 * 8]);
    gload16(A + (size_t)rowA1 * K + k0 + sl1 * 8, &As[idx1 * 8]);
    gload16(B + (size_t)(n0 + r1) * K + k0 + sl1 * 8, &Bs[idx1 * 8]);
    __syncthreads();
    bf16x8 av[4], bv[4];
#pragma unroll
    for (int mi = 0; mi < 4; ++mi) {
      const int r = wr + mi * 16 + fr;
      av[mi] = *reinterpret_cast<const bf16x8*>(&As[r * 32 + ((fs + (r >> 1)) & 3) * 8]);
    }
#pragma unroll
    for (int ni = 0; ni < 4; ++ni) {
      const int r = wc + ni * 16 + fr;
      bv[ni] = *reinterpret_cast<const bf16x8*>(&Bs[r * 32 + ((fs + (r >> 1)) & 3) * 8]);
    }
#pragma unroll
    for (int mi = 0; mi < 4; ++mi)
#pragma unroll
      for (int ni = 0; ni < 4; ++ni)
        acc[mi][ni] = __builtin_amdgcn_mfma_f32_16x16x32_bf16(av[mi], bv[ni],
                                                              acc[mi][ni], 0, 0, 0);
    __syncthreads();
  }

#pragma unroll
  for (int ni = 0; ni < 4; ++ni) {
    const int col = n0 + wc + ni * 16 + fr;
    const float bb = bias[col];
#pragma unroll
    for (int mi = 0; mi < 4; ++mi) {
      const f32x4 c = acc[mi][ni];
#pragma unroll
      for (int i = 0; i < 4; ++i) {
        const int row = m0 + wr + mi * 16 + fs * 4 + i;
        if (row < N_NODES) {
          if constexpr (MODE == 0) {
            float v = c[i] + bb;
            v = v > 0.f ? v : 0.f;
            outS[(size_t)row * ostride + ooff + col] = f2bf(v);
          } else {
            outF[(size_t)row * HD + col] = c[i] + bb;
          }
        }
      }
    }
  }
}

// ---------------- pool: GR[g] = mean over rows [rstart[g], rstart[g+1]) ------
__global__ __launch_bounds__(256) void k_pool(const float* __restrict__ X2,
                                              const int* __restrict__ rstart,
                                              float* __restrict__ GR) {
  const int g = blockIdx.x, t = threadIdx.x;
  const int s0 = rstart[g], s1 = rstart[g + 1];
  float a0 = 0.f, a1 = 0.f;
  for (int r = s0; r < s1; ++r) {
    a0 += X2[(size_t)r * HD + t];
    a1 += X2[(size_t)r * HD + t + 256];
  }
  const float inv = 1.0f / fmaxf((float)(s1 - s0), 1.0f);
  GR[g * HD + t]       = a0 * inv;
  GR[g * HD + t + 256] = a1 * inv;
}

// ---------------- classifier: 4 graphs / block ----------------
__global__ __launch_bounds__(256) void k_classifier(
    const float* __restrict__ GR,
    const float* __restrict__ Wc1T, const float* __restrict__ bc1,
    const float* __restrict__ Wc2T, const float* __restrict__ bc2,
    float* __restrict__ out) {
  __shared__ float gr[4][HD];
  __shared__ float hs[4][HD];
  const int t = threadIdx.x;
  const int g0 = blockIdx.x * 4;
  for (int f = t; f < 4 * HD; f += 256) {
    int r = f >> 9, c = f & 511;
    gr[r][c] = GR[(g0 + r) * HD + c];
  }
  __syncthreads();
  const int w = t >> 6, lane = t & 63, c0 = lane * 8;
  {
    float acc[8];
#pragma unroll
    for (int j = 0; j < 8; ++j) acc[j] = 0.0f;
#pragma unroll 2
    for (int k = 0; k < HD; ++k) {
      const float4 w0 = *reinterpret_cast<const float4*>(&Wc1T[k * HD + c0]);
      const float4 w1 = *reinterpret_cast<const float4*>(&Wc1T[k * HD + c0 + 4]);
      const float g = gr[w][k];
      acc[0] = fmaf(w0.x, g, acc[0]); acc[1] = fmaf(w0.y, g, acc[1]);
      acc[2] = fmaf(w0.z, g, acc[2]); acc[3] = fmaf(w0.w, g, acc[3]);
      acc[4] = fmaf(w1.x, g, acc[4]); acc[5] = fmaf(w1.y, g, acc[5]);
      acc[6] = fmaf(w1.z, g, acc[6]); acc[7] = fmaf(w1.w, g, acc[7]);
    }
#pragma unroll
    for (int j = 0; j < 8; ++j)
      hs[w][c0 + j] = fmaxf(acc[j] + bc1[c0 + j], 0.0f);
  }
  __syncthreads();
  for (int ci = 0; ci < 4; ++ci) {
    int c = t + ci * 256;
    if (c < NTAC) {
      float a0 = 0.f, a1 = 0.f, a2 = 0.f, a3 = 0.f;
      for (int k = 0; k < HD; ++k) {
        const float wv = Wc2T[k * NTAC + c];
        a0 = fmaf(hs[0][k], wv, a0);
        a1 = fmaf(hs[1][k], wv, a1);
        a2 = fmaf(hs[2][k], wv, a2);
        a3 = fmaf(hs[3][k], wv, a3);
      }
      const float b = bc2[c];
      out[(g0 + 0) * NTAC + c] = a0 + b;
      out[(g0 + 1) * NTAC + c] = a1 + b;
      out[(g0 + 2) * NTAC + c] = a2 + b;
      out[(g0 + 3) * NTAC + c] = a3 + b;
    }
  }
}

extern "C" void kernel_launch(void* const* d_in, const int* in_sizes, int n_in,
                              void* d_out, int out_size, void* d_ws, size_t ws_size,
                              hipStream_t stream) {
  const int*   node_type = (const int*)d_in[0];
  const int*   node_tac  = (const int*)d_in[1];
  const int*   edge      = (const int*)d_in[2];
  const int*   batch     = (const int*)d_in[3];
  const float* temb      = (const float*)d_in[4];
  const float* tacemb    = (const float*)d_in[5];
  const float* W1l       = (const float*)d_in[6];
  const float* b1l       = (const float*)d_in[7];
  const float* W1r       = (const float*)d_in[8];
  const float* W2l       = (const float*)d_in[9];
  const float* b2l       = (const float*)d_in[10];
  const float* W2r       = (const float*)d_in[11];
  const float* Wc1       = (const float*)d_in[12];
  const float* bc1       = (const float*)d_in[13];
  const float* Wc2       = (const float*)d_in[14];
  const float* bc2       = (const float*)d_in[15];
  const int* src = edge;
  const int* dst = edge + N_EDGES;

  // ---- workspace layout ----
  char* p = (char*)d_ws;
  int*   DEG    = (int*)p;    p += N_NODES * 4;            // zeroed
  int*   CUR    = (int*)p;    p += N_NODES * 4;            // zeroed
  size_t zero_bytes = (size_t)(2 * N_NODES) * 4;
  int*   ROWS   = (int*)p;    p += (N_NODES + 4) * 4;
  int*   RSTART = (int*)p;    p += (NGRAPH + 4) * 4;
  int*   ESRC   = (int*)p;    p += N_EDGES * 4;
  short* A1     = (short*)p;  p += (size_t)N_NODES * 192 * 2;   // [agg1 | x]
  short* A2     = (short*)p;  p += (size_t)N_NODES * 1024 * 2;  // [agg2 | x1]
  float* X2     = (float*)p;  p += (size_t)N_NODES * HD * 4;
  float* GR     = (float*)p;  p += NGRAPH * HD * 4;
  short* BC1    = (short*)p;  p += HD * 192 * 2;
  short* BC2    = (short*)p;  p += HD * 1024 * 2;
  float* WC1T   = (float*)p;  p += HD * HD * 4;
  float* WC2T   = (float*)p;  p += HD * NTAC * 4;

  hipMemsetAsync(d_ws, 0, zero_bytes, stream);

  // weight prep
  k_bcat<<<(HD * 192 / 4 + 255) / 256, 256, 0, stream>>>(W1l, W1r, BC1, 96, 192);
  k_bcat<<<(HD * 1024 / 4 + 255) / 256, 256, 0, stream>>>(W2l, W2r, BC2, 512, 1024);
  k_transpose<<<(HD * HD + 255) / 256, 256, 0, stream>>>(Wc1, WC1T, HD, HD);
  k_transpose<<<(NTAC * HD + 255) / 256, 256, 0, stream>>>(Wc2, WC2T, NTAC, HD);

  // CSR + graph bounds
  k_degree<<<N_EDGES / 256, 256, 0, stream>>>(dst, DEG);
  k_scan<<<1, 1024, 0, stream>>>(DEG, ROWS);
  k_scatter<<<N_EDGES / 256, 256, 0, stream>>>(src, dst, ROWS, CUR, ESRC);
  k_gbounds<<<(N_NODES + 255) / 256, 256, 0, stream>>>(batch, RSTART);

  // forward
  k_embed<<<(N_NODES * 24) / 256, 256, 0, stream>>>(node_type, node_tac, temb, tacemb, A1);
  k_gather96<<<(N_NODES * 24) / 256, 256, 0, stream>>>(ROWS, ESRC, A1);
  dim3 gemm_grid((N_NODES + 127) / 128, 4);
  k_gemm<192, 0><<<gemm_grid, 256, 0, stream>>>(A1, BC1, b1l, A2, nullptr, 1024, 512);
  k_gather512<<<(N_NODES * 64) / 256, 256, 0, stream>>>(ROWS, ESRC, A2);
  k_gemm<1024, 1><<<gemm_grid, 256, 0, stream>>>(A2, BC2, b2l, nullptr, X2, 0, 0);
  k_pool<<<NGRAPH, 256, 0, stream>>>(X2, RSTART, GR);
  k_classifier<<<NGRAPH / 4, 256, 0, stream>>>(GR, WC1T, bc1, WC2T, bc2, (float*)d_out);
}

// Round 4
// 330.791 us; speedup vs baseline: 10.4389x; 1.3828x over previous
//
#include <hip/hip_runtime.h>

#define N_NODES 20000
#define N_EDGES 320000
#define NGRAPH  256
#define NTAC    1000
#define HD      512

typedef __attribute__((ext_vector_type(8))) short bf16x8;
typedef __attribute__((ext_vector_type(4))) short short4v;
typedef __attribute__((ext_vector_type(4))) float f32x4;

__device__ __forceinline__ short f2bf(float f) {      // RNE float->bf16
  union { float f; unsigned u; } v; v.f = f;
  unsigned r = v.u + 0x7FFFu + ((v.u >> 16) & 1u);
  return (short)(r >> 16);
}
__device__ __forceinline__ float bf2f(short s) {
  union { unsigned u; float f; } v;
  v.u = ((unsigned)(unsigned short)s) << 16;
  return v.f;
}
__device__ __forceinline__ void gload16(const void* g, void* l) {
  __builtin_amdgcn_global_load_lds((const __attribute__((address_space(1))) void*)g,
                                   (__attribute__((address_space(3))) void*)l,
                                   16, 0, 0);
}

// ---------------- transpose: in[R,C] -> out[C,R] (classifier weights, fp32) ----
__global__ void k_transpose(const float* __restrict__ in, float* __restrict__ out,
                            int R, int C) {
  int idx = blockIdx.x * 256 + threadIdx.x;
  if (idx < R * C) {
    int r = idx / C, c = idx - r * C;
    out[c * R + r] = in[idx];
  }
}

// ---------------- Bcat[n][Ktot] = [Wl[n][0:Kl] | Wr[n][...]] fp32->bf16 ------
__global__ void k_bcat(const float* __restrict__ Wl, const float* __restrict__ Wr,
                       short* __restrict__ Bc, int Kl, int Ktot) {
  int tid = blockIdx.x * 256 + threadIdx.x;
  int kq = Ktot >> 2;
  int n = tid / kq, k4 = (tid - n * kq) << 2;
  if (n >= HD) return;
  const float* srcp = (k4 < Kl) ? &Wl[(size_t)n * Kl + k4]
                                : &Wr[(size_t)n * (Ktot - Kl) + (k4 - Kl)];
  float4 v = *reinterpret_cast<const float4*>(srcp);
  short4v o; o[0] = f2bf(v.x); o[1] = f2bf(v.y); o[2] = f2bf(v.z); o[3] = f2bf(v.w);
  *reinterpret_cast<short4v*>(&Bc[(size_t)n * Ktot + k4]) = o;
}

// ---------------- embedding concat -> bf16 into A1[:,96:192] -------------------
__global__ void k_embed(const int* __restrict__ ntype, const int* __restrict__ ntac,
                        const float* __restrict__ temb, const float* __restrict__ tacemb,
                        short* __restrict__ A1) {
  int tid = blockIdx.x * 256 + threadIdx.x;
  int node = tid / 24;
  int j = tid - node * 24;
  if (node >= N_NODES) return;
  float4 v;
  int col;
  if (j < 8) {
    int t = ntype[node];
    v = *reinterpret_cast<const float4*>(&temb[t * 32 + j * 4]);
    col = j * 4;
  } else {
    int s = ntac[node] + 1;
    s = s < 0 ? 0 : (s > NTAC ? NTAC : s);
    v = *reinterpret_cast<const float4*>(&tacemb[s * 64 + (j - 8) * 4]);
    col = 32 + (j - 8) * 4;
  }
  short4v o; o[0] = f2bf(v.x); o[1] = f2bf(v.y); o[2] = f2bf(v.z); o[3] = f2bf(v.w);
  *reinterpret_cast<short4v*>(&A1[(size_t)node * 192 + 96 + col]) = o;
}

// ---------------- CSR build ----------------
__global__ void k_degree(const int* __restrict__ dst, int* __restrict__ deg) {
  int e = blockIdx.x * 256 + threadIdx.x;
  if (e < N_EDGES) atomicAdd(&deg[dst[e]], 1);
}

__global__ __launch_bounds__(1024) void k_scan(const int* __restrict__ deg,
                                               int* __restrict__ rowstart) {
  __shared__ int partial[1024];
  const int t = threadIdx.x;
  const int CH = (N_NODES + 1023) / 1024;  // 20
  int s = 0;
  for (int i = 0; i < CH; ++i) {
    int idx = t * CH + i;
    if (idx < N_NODES) s += deg[idx];
  }
  partial[t] = s;
  __syncthreads();
  for (int off = 1; off < 1024; off <<= 1) {
    int v = (t >= off) ? partial[t - off] : 0;
    __syncthreads();
    partial[t] += v;
    __syncthreads();
  }
  int run = (t == 0) ? 0 : partial[t - 1];
  for (int i = 0; i < CH; ++i) {
    int idx = t * CH + i;
    if (idx < N_NODES) { rowstart[idx] = run; run += deg[idx]; }
  }
  if (t == 1023) rowstart[N_NODES] = run;
}

__global__ void k_scatter(const int* __restrict__ src, const int* __restrict__ dst,
                          const int* __restrict__ rowstart, int* __restrict__ cur,
                          int* __restrict__ esrc) {
  int e = blockIdx.x * 256 + threadIdx.x;
  if (e < N_EDGES) {
    int d = dst[e];
    int p = rowstart[d] + atomicAdd(&cur[d], 1);
    esrc[p] = src[e];
  }
}

// ---------------- graph row ranges (batch is sorted) ----------------
__global__ void k_gbounds(const int* __restrict__ batch, int* __restrict__ rstart) {
  int i = blockIdx.x * 256 + threadIdx.x;
  if (i >= N_NODES) return;
  int b = batch[i];
  int bp = (i == 0) ? -1 : batch[i - 1];
  for (int g = bp + 1; g <= b; ++g) rstart[g] = i;
  if (i == N_NODES - 1)
    for (int g = b + 1; g <= NGRAPH; ++g) rstart[g] = N_NODES;
}

// ---------------- gather-mean D=96: A1[:,0:96] = mean nbr A1[:,96:192] --------
__global__ __launch_bounds__(256) void k_gather96(
    const int* __restrict__ rowstart, const int* __restrict__ esrc,
    short* __restrict__ A1) {
  int tid = blockIdx.x * 256 + threadIdx.x;
  int node = tid / 24;
  int c = (tid - node * 24) * 4;
  if (node >= N_NODES) return;
  const int s0 = rowstart[node], s1 = rowstart[node + 1];
  float a0 = 0.f, a1 = 0.f, a2 = 0.f, a3 = 0.f;
  for (int i = s0; i < s1; ++i) {
    int nbr = esrc[i];
    short4v v = *reinterpret_cast<const short4v*>(&A1[(size_t)nbr * 192 + 96 + c]);
    a0 += bf2f(v[0]); a1 += bf2f(v[1]); a2 += bf2f(v[2]); a3 += bf2f(v[3]);
  }
  const float inv = 1.0f / fmaxf((float)(s1 - s0), 1.0f);
  short4v o; o[0] = f2bf(a0 * inv); o[1] = f2bf(a1 * inv);
  o[2] = f2bf(a2 * inv); o[3] = f2bf(a3 * inv);
  *reinterpret_cast<short4v*>(&A1[(size_t)node * 192 + c]) = o;
}

// ---------------- gather-mean D=512: A2[:,0:512] = mean nbr A2[:,512:1024] ----
__global__ __launch_bounds__(256) void k_gather512(
    const int* __restrict__ rowstart, const int* __restrict__ esrc,
    short* __restrict__ A2) {
  int tid = blockIdx.x * 256 + threadIdx.x;
  int node = tid >> 6;
  int c = (tid & 63) << 3;
  const int s0 = rowstart[node], s1 = rowstart[node + 1];
  float acc[8] = {0.f, 0.f, 0.f, 0.f, 0.f, 0.f, 0.f, 0.f};
  for (int i = s0; i < s1; ++i) {
    int nbr = esrc[i];
    bf16x8 v = *reinterpret_cast<const bf16x8*>(&A2[(size_t)nbr * 1024 + 512 + c]);
#pragma unroll
    for (int j = 0; j < 8; ++j) acc[j] += bf2f(v[j]);
  }
  const float inv = 1.0f / fmaxf((float)(s1 - s0), 1.0f);
  bf16x8 o;
#pragma unroll
  for (int j = 0; j < 8; ++j) o[j] = f2bf(acc[j] * inv);
  *reinterpret_cast<bf16x8*>(&A2[(size_t)node * 1024 + c]) = o;
}

// ---------------- bf16 MFMA GEMM: C[M,512] = A[M,K] @ B[512,K]^T + bias -------
// MODE 0: relu, store bf16 to outS[row*ostride + ooff + col] (layer1 -> A2 x1-half)
// MODE 1: store fp32 to outF[row*512 + col]                  (layer2 -> X2)
template<int K, int MODE>
__global__ __launch_bounds__(256) void k_gemm(
    const short* __restrict__ A, const short* __restrict__ B,
    const float* __restrict__ bias,
    short* __restrict__ outS, float* __restrict__ outF,
    int ostride, int ooff) {
  __shared__ short As[128 * 32];
  __shared__ short Bs[128 * 32];
  const int t = threadIdx.x;
  const int m0 = blockIdx.x * 128;
  const int n0 = blockIdx.y * 128;
  const int l = t & 63, wid = t >> 6;
  const int wr = (wid >> 1) * 64, wc = (wid & 1) * 64;
  const int fr = l & 15, fs = l >> 4;

  f32x4 acc[4][4];
#pragma unroll
  for (int a = 0; a < 4; ++a)
#pragma unroll
    for (int b = 0; b < 4; ++b) acc[a][b] = (f32x4){0.f, 0.f, 0.f, 0.f};

  // staging geometry (swizzled source -> linear LDS; idx = r*4 + phys_slot)
  const int idx0 = t, r0 = idx0 >> 2, sp0 = idx0 & 3;
  const int sl0 = (sp0 - (r0 >> 1)) & 3;
  const int idx1 = t + 256, r1 = idx1 >> 2, sp1 = idx1 & 3;
  const int sl1 = (sp1 - (r1 >> 1)) & 3;
  int rowA0 = m0 + r0; rowA0 = rowA0 < N_NODES ? rowA0 : N_NODES - 1;
  int rowA1 = m0 + r1; rowA1 = rowA1 < N_NODES ? rowA1 : N_NODES - 1;

  for (int k0 = 0; k0 < K; k0 += 32) {
    gload16(A + (size_t)rowA0 * K + k0 + sl0 * 8, &As[idx0 * 8]);
    gload16(B + (size_t)(n0 + r0) * K + k0 + sl0 * 8, &Bs[idx0 * 8]);
    gload16(A + (size_t)rowA1 * K + k0 + sl1 * 8, &As[idx1 * 8]);
    gload16(B + (size_t)(n0 + r1) * K + k0 + sl1 * 8, &Bs[idx1 * 8]);
    __syncthreads();
    bf16x8 av[4], bv[4];
#pragma unroll
    for (int mi = 0; mi < 4; ++mi) {
      const int r = wr + mi * 16 + fr;
      av[mi] = *reinterpret_cast<const bf16x8*>(&As[r * 32 + ((fs + (r >> 1)) & 3) * 8]);
    }
#pragma unroll
    for (int ni = 0; ni < 4; ++ni) {
      const int r = wc + ni * 16 + fr;
      bv[ni] = *reinterpret_cast<const bf16x8*>(&Bs[r * 32 + ((fs + (r >> 1)) & 3) * 8]);
    }
#pragma unroll
    for (int mi = 0; mi < 4; ++mi)
#pragma unroll
      for (int ni = 0; ni < 4; ++ni)
        acc[mi][ni] = __builtin_amdgcn_mfma_f32_16x16x32_bf16(av[mi], bv[ni],
                                                              acc[mi][ni], 0, 0, 0);
    __syncthreads();
  }

#pragma unroll
  for (int ni = 0; ni < 4; ++ni) {
    const int col = n0 + wc + ni * 16 + fr;
    const float bb = bias[col];
#pragma unroll
    for (int mi = 0; mi < 4; ++mi) {
      const f32x4 c = acc[mi][ni];
#pragma unroll
      for (int i = 0; i < 4; ++i) {
        const int row = m0 + wr + mi * 16 + fs * 4 + i;
        if (row < N_NODES) {
          if constexpr (MODE == 0) {
            float v = c[i] + bb;
            v = v > 0.f ? v : 0.f;
            outS[(size_t)row * ostride + ooff + col] = f2bf(v);
          } else {
            outF[(size_t)row * HD + col] = c[i] + bb;
          }
        }
      }
    }
  }
}

// ---------------- pool: GR[g] = mean over rows [rstart[g], rstart[g+1]) ------
__global__ __launch_bounds__(256) void k_pool(const float* __restrict__ X2,
                                              const int* __restrict__ rstart,
                                              float* __restrict__ GR) {
  const int g = blockIdx.x, t = threadIdx.x;
  const int s0 = rstart[g], s1 = rstart[g + 1];
  float a0 = 0.f, a1 = 0.f;
  for (int r = s0; r < s1; ++r) {
    a0 += X2[(size_t)r * HD + t];
    a1 += X2[(size_t)r * HD + t + 256];
  }
  const float inv = 1.0f / fmaxf((float)(s1 - s0), 1.0f);
  GR[g * HD + t]       = a0 * inv;
  GR[g * HD + t + 256] = a1 * inv;
}

// ---------------- classifier MLP layer 1: h = relu(GR @ Wc1^T + bc1) ---------
// grid (NGRAPH, 2); one output element per thread, 8 loads in flight
__global__ __launch_bounds__(256) void k_mlp1(
    const float* __restrict__ GR, const float* __restrict__ Wc1T,
    const float* __restrict__ bc1, float* __restrict__ HS) {
  __shared__ float grs[HD];
  const int g = blockIdx.x;
  const int t = threadIdx.x;
  const int c = blockIdx.y * 256 + t;
  grs[t]       = GR[g * HD + t];
  grs[t + 256] = GR[g * HD + t + 256];
  __syncthreads();
  float acc = 0.f;
#pragma unroll 8
  for (int k = 0; k < HD; ++k)
    acc = fmaf(Wc1T[k * HD + c], grs[k], acc);
  HS[g * HD + c] = fmaxf(acc + bc1[c], 0.f);
}

// ---------------- classifier MLP layer 2: out = HS @ Wc2^T + bc2 -------------
// grid (NGRAPH, 4)
__global__ __launch_bounds__(256) void k_mlp2(
    const float* __restrict__ HS, const float* __restrict__ Wc2T,
    const float* __restrict__ bc2, float* __restrict__ out) {
  __shared__ float hsm[HD];
  const int g = blockIdx.x;
  const int t = threadIdx.x;
  const int c = blockIdx.y * 256 + t;
  hsm[t]       = HS[g * HD + t];
  hsm[t + 256] = HS[g * HD + t + 256];
  __syncthreads();
  if (c < NTAC) {
    float acc = 0.f;
#pragma unroll 8
    for (int k = 0; k < HD; ++k)
      acc = fmaf(Wc2T[k * NTAC + c], hsm[k], acc);
    out[g * NTAC + c] = acc + bc2[c];
  }
}

extern "C" void kernel_launch(void* const* d_in, const int* in_sizes, int n_in,
                              void* d_out, int out_size, void* d_ws, size_t ws_size,
                              hipStream_t stream) {
  const int*   node_type = (const int*)d_in[0];
  const int*   node_tac  = (const int*)d_in[1];
  const int*   edge      = (const int*)d_in[2];
  const int*   batch     = (const int*)d_in[3];
  const float* temb      = (const float*)d_in[4];
  const float* tacemb    = (const float*)d_in[5];
  const float* W1l       = (const float*)d_in[6];
  const float* b1l       = (const float*)d_in[7];
  const float* W1r       = (const float*)d_in[8];
  const float* W2l       = (const float*)d_in[9];
  const float* b2l       = (const float*)d_in[10];
  const float* W2r       = (const float*)d_in[11];
  const float* Wc1       = (const float*)d_in[12];
  const float* bc1       = (const float*)d_in[13];
  const float* Wc2       = (const float*)d_in[14];
  const float* bc2       = (const float*)d_in[15];
  const int* src = edge;
  const int* dst = edge + N_EDGES;

  // ---- workspace layout ----
  char* p = (char*)d_ws;
  int*   DEG    = (int*)p;    p += N_NODES * 4;            // zeroed
  int*   CUR    = (int*)p;    p += N_NODES * 4;            // zeroed
  size_t zero_bytes = (size_t)(2 * N_NODES) * 4;
  int*   ROWS   = (int*)p;    p += (N_NODES + 4) * 4;
  int*   RSTART = (int*)p;    p += (NGRAPH + 4) * 4;
  int*   ESRC   = (int*)p;    p += N_EDGES * 4;
  short* A1     = (short*)p;  p += (size_t)N_NODES * 192 * 2;   // [agg1 | x]
  short* A2     = (short*)p;  p += (size_t)N_NODES * 1024 * 2;  // [agg2 | x1]
  float* X2     = (float*)p;  p += (size_t)N_NODES * HD * 4;
  float* GR     = (float*)p;  p += NGRAPH * HD * 4;
  float* HS     = (float*)p;  p += NGRAPH * HD * 4;
  short* BC1    = (short*)p;  p += HD * 192 * 2;
  short* BC2    = (short*)p;  p += HD * 1024 * 2;
  float* WC1T   = (float*)p;  p += HD * HD * 4;
  float* WC2T   = (float*)p;  p += HD * NTAC * 4;

  hipMemsetAsync(d_ws, 0, zero_bytes, stream);

  // weight prep
  k_bcat<<<(HD * 192 / 4 + 255) / 256, 256, 0, stream>>>(W1l, W1r, BC1, 96, 192);
  k_bcat<<<(HD * 1024 / 4 + 255) / 256, 256, 0, stream>>>(W2l, W2r, BC2, 512, 1024);
  k_transpose<<<(HD * HD + 255) / 256, 256, 0, stream>>>(Wc1, WC1T, HD, HD);
  k_transpose<<<(NTAC * HD + 255) / 256, 256, 0, stream>>>(Wc2, WC2T, NTAC, HD);

  // CSR + graph bounds
  k_degree<<<N_EDGES / 256, 256, 0, stream>>>(dst, DEG);
  k_scan<<<1, 1024, 0, stream>>>(DEG, ROWS);
  k_scatter<<<N_EDGES / 256, 256, 0, stream>>>(src, dst, ROWS, CUR, ESRC);
  k_gbounds<<<(N_NODES + 255) / 256, 256, 0, stream>>>(batch, RSTART);

  // forward
  k_embed<<<(N_NODES * 24) / 256, 256, 0, stream>>>(node_type, node_tac, temb, tacemb, A1);
  k_gather96<<<(N_NODES * 24) / 256, 256, 0, stream>>>(ROWS, ESRC, A1);
  dim3 gemm_grid((N_NODES + 127) / 128, 4);
  k_gemm<192, 0><<<gemm_grid, 256, 0, stream>>>(A1, BC1, b1l, A2, nullptr, 1024, 512);
  k_gather512<<<(N_NODES * 64) / 256, 256, 0, stream>>>(ROWS, ESRC, A2);
  k_gemm<1024, 1><<<gemm_grid, 256, 0, stream>>>(A2, BC2, b2l, nullptr, X2, 0, 0);
  k_pool<<<NGRAPH, 256, 0, stream>>>(X2, RSTART, GR);
  k_mlp1<<<dim3(NGRAPH, 2), 256, 0, stream>>>(GR, WC1T, bc1, HS);
  k_mlp2<<<dim3(NGRAPH, 4), 256, 0, stream>>>(HS, WC2T, bc2, (float*)d_out);
}

// Round 5
// 289.048 us; speedup vs baseline: 11.9465x; 1.1444x over previous
//
#include <hip/hip_runtime.h>

#define N_NODES 20000
#define N_EDGES 320000
#define NGRAPH  256
#define NTAC    1000
#define HD      512

typedef __attribute__((ext_vector_type(8))) short bf16x8;
typedef __attribute__((ext_vector_type(4))) short short4v;
typedef __attribute__((ext_vector_type(4))) float f32x4;

__device__ __forceinline__ short f2bf(float f) {      // RNE float->bf16
  union { float f; unsigned u; } v; v.f = f;
  unsigned r = v.u + 0x7FFFu + ((v.u >> 16) & 1u);
  return (short)(r >> 16);
}
__device__ __forceinline__ float bf2f(short s) {
  union { unsigned u; float f; } v;
  v.u = ((unsigned)(unsigned short)s) << 16;
  return v.f;
}
__device__ __forceinline__ void gload16(const void* g, void* l) {
  __builtin_amdgcn_global_load_lds((const __attribute__((address_space(1))) void*)g,
                                   (__attribute__((address_space(3))) void*)l,
                                   16, 0, 0);
}

// ---------------- merged weight prep: Wc1^T, Wc2^T (fp32), BC1, BC2 (bf16) ----
__global__ void k_prep(const float* __restrict__ Wc1, const float* __restrict__ Wc2,
                       float* __restrict__ WC1T, float* __restrict__ WC2T,
                       const float* __restrict__ W1l, const float* __restrict__ W1r,
                       short* __restrict__ BC1,
                       const float* __restrict__ W2l, const float* __restrict__ W2r,
                       short* __restrict__ BC2) {
  int idx = blockIdx.x * 256 + threadIdx.x;
  const int S0 = HD * HD;          // Wc1 transpose (elems)
  const int S1 = NTAC * HD;        // Wc2 transpose (elems)
  const int S2 = HD * 192 / 4;     // bcat1 (quads)
  const int S3 = HD * 1024 / 4;    // bcat2 (quads)
  if (idx < S0) {
    int r = idx >> 9, c = idx & 511;
    WC1T[c * HD + r] = Wc1[idx];
  } else if ((idx -= S0) < S1) {
    int r = idx / HD, c = idx - r * HD;
    WC2T[c * NTAC + r] = Wc2[idx];
  } else if ((idx -= S1) < S2) {
    int n = idx / 48, k4 = (idx - n * 48) << 2;
    const float* s = (k4 < 96) ? &W1l[(size_t)n * 96 + k4]
                               : &W1r[(size_t)n * 96 + (k4 - 96)];
    float4 v = *reinterpret_cast<const float4*>(s);
    short4v o = {f2bf(v.x), f2bf(v.y), f2bf(v.z), f2bf(v.w)};
    *reinterpret_cast<short4v*>(&BC1[(size_t)n * 192 + k4]) = o;
  } else if ((idx -= S2) < S3) {
    int n = idx >> 8, k4 = (idx & 255) << 2;
    const float* s = (k4 < 512) ? &W2l[(size_t)n * 512 + k4]
                                : &W2r[(size_t)n * 512 + (k4 - 512)];
    float4 v = *reinterpret_cast<const float4*>(s);
    short4v o = {f2bf(v.x), f2bf(v.y), f2bf(v.z), f2bf(v.w)};
    *reinterpret_cast<short4v*>(&BC2[(size_t)n * 1024 + k4]) = o;
  }
}

// ---------------- embedding concat -> bf16 into A1[:,96:192] -------------------
__global__ void k_embed(const int* __restrict__ ntype, const int* __restrict__ ntac,
                        const float* __restrict__ temb, const float* __restrict__ tacemb,
                        short* __restrict__ A1) {
  int tid = blockIdx.x * 256 + threadIdx.x;
  int node = tid / 24;
  int j = tid - node * 24;
  if (node >= N_NODES) return;
  float4 v;
  int col;
  if (j < 8) {
    int t = ntype[node];
    v = *reinterpret_cast<const float4*>(&temb[t * 32 + j * 4]);
    col = j * 4;
  } else {
    int s = ntac[node] + 1;
    s = s < 0 ? 0 : (s > NTAC ? NTAC : s);
    v = *reinterpret_cast<const float4*>(&tacemb[s * 64 + (j - 8) * 4]);
    col = 32 + (j - 8) * 4;
  }
  short4v o = {f2bf(v.x), f2bf(v.y), f2bf(v.z), f2bf(v.w)};
  *reinterpret_cast<short4v*>(&A1[(size_t)node * 192 + 96 + col]) = o;
}

// ---------------- CSR build ----------------
__global__ void k_degree(const int* __restrict__ dst, int* __restrict__ deg) {
  int e = blockIdx.x * 256 + threadIdx.x;
  if (e < N_EDGES) atomicAdd(&deg[dst[e]], 1);
}

__global__ __launch_bounds__(1024) void k_scan(const int* __restrict__ deg,
                                               int* __restrict__ rowstart) {
  __shared__ int partial[1024];
  const int t = threadIdx.x;
  const int CH = (N_NODES + 1023) / 1024;  // 20
  int s = 0;
  for (int i = 0; i < CH; ++i) {
    int idx = t * CH + i;
    if (idx < N_NODES) s += deg[idx];
  }
  partial[t] = s;
  __syncthreads();
  for (int off = 1; off < 1024; off <<= 1) {
    int v = (t >= off) ? partial[t - off] : 0;
    __syncthreads();
    partial[t] += v;
    __syncthreads();
  }
  int run = (t == 0) ? 0 : partial[t - 1];
  for (int i = 0; i < CH; ++i) {
    int idx = t * CH + i;
    if (idx < N_NODES) { rowstart[idx] = run; run += deg[idx]; }
  }
  if (t == 1023) rowstart[N_NODES] = run;
}

__global__ void k_scatter(const int* __restrict__ src, const int* __restrict__ dst,
                          const int* __restrict__ rowstart, int* __restrict__ cur,
                          int* __restrict__ esrc) {
  int e = blockIdx.x * 256 + threadIdx.x;
  if (e < N_EDGES) {
    int d = dst[e];
    int p = rowstart[d] + atomicAdd(&cur[d], 1);
    esrc[p] = src[e];
  }
}

// ---------------- graph row ranges (batch is sorted) ----------------
__global__ void k_gbounds(const int* __restrict__ batch, int* __restrict__ rstart) {
  int i = blockIdx.x * 256 + threadIdx.x;
  if (i >= N_NODES) return;
  int b = batch[i];
  int bp = (i == 0) ? -1 : batch[i - 1];
  for (int g = bp + 1; g <= b; ++g) rstart[g] = i;
  if (i == N_NODES - 1)
    for (int g = b + 1; g <= NGRAPH; ++g) rstart[g] = N_NODES;
}

// ---------------- gather-mean D=96: A1[:,0:96] = mean nbr A1[:,96:192] --------
__global__ __launch_bounds__(256) void k_gather96(
    const int* __restrict__ rowstart, const int* __restrict__ esrc,
    short* __restrict__ A1) {
  int tid = blockIdx.x * 256 + threadIdx.x;
  int node = tid / 24;
  int c = (tid - node * 24) * 4;
  if (node >= N_NODES) return;
  const int s0 = rowstart[node], s1 = rowstart[node + 1];
  float a0 = 0.f, a1 = 0.f, a2 = 0.f, a3 = 0.f;
  for (int i = s0; i < s1; ++i) {
    int nbr = esrc[i];
    short4v v = *reinterpret_cast<const short4v*>(&A1[(size_t)nbr * 192 + 96 + c]);
    a0 += bf2f(v[0]); a1 += bf2f(v[1]); a2 += bf2f(v[2]); a3 += bf2f(v[3]);
  }
  const float inv = 1.0f / fmaxf((float)(s1 - s0), 1.0f);
  short4v o = {f2bf(a0 * inv), f2bf(a1 * inv), f2bf(a2 * inv), f2bf(a3 * inv)};
  *reinterpret_cast<short4v*>(&A1[(size_t)node * 192 + c]) = o;
}

// ---------------- gather-mean D=512: A2[:,0:512] = mean nbr A2[:,512:1024] ----
__global__ __launch_bounds__(256) void k_gather512(
    const int* __restrict__ rowstart, const int* __restrict__ esrc,
    short* __restrict__ A2) {
  int tid = blockIdx.x * 256 + threadIdx.x;
  int node = tid >> 6;
  int c = (tid & 63) << 3;
  const int s0 = rowstart[node], s1 = rowstart[node + 1];
  float acc0[8] = {0.f, 0.f, 0.f, 0.f, 0.f, 0.f, 0.f, 0.f};
  float acc1[8] = {0.f, 0.f, 0.f, 0.f, 0.f, 0.f, 0.f, 0.f};
  int i = s0;
  for (; i + 2 <= s1; i += 2) {
    int nbr0 = esrc[i], nbr1 = esrc[i + 1];
    bf16x8 v0 = *reinterpret_cast<const bf16x8*>(&A2[(size_t)nbr0 * 1024 + 512 + c]);
    bf16x8 v1 = *reinterpret_cast<const bf16x8*>(&A2[(size_t)nbr1 * 1024 + 512 + c]);
#pragma unroll
    for (int j = 0; j < 8; ++j) { acc0[j] += bf2f(v0[j]); acc1[j] += bf2f(v1[j]); }
  }
  if (i < s1) {
    int nbr = esrc[i];
    bf16x8 v = *reinterpret_cast<const bf16x8*>(&A2[(size_t)nbr * 1024 + 512 + c]);
#pragma unroll
    for (int j = 0; j < 8; ++j) acc0[j] += bf2f(v[j]);
  }
  const float inv = 1.0f / fmaxf((float)(s1 - s0), 1.0f);
  bf16x8 o;
#pragma unroll
  for (int j = 0; j < 8; ++j) o[j] = f2bf((acc0[j] + acc1[j]) * inv);
  *reinterpret_cast<bf16x8*>(&A2[(size_t)node * 1024 + c]) = o;
}

// ---------------- bf16 MFMA GEMM, double-buffered 2-phase, XCD-swizzled -------
// C[M,512] = A[M,K] @ B[512,K]^T + bias; RELU then store bf16.
template<int K, bool RELU>
__global__ __launch_bounds__(256) void k_gemm(
    const short* __restrict__ A, const short* __restrict__ B,
    const float* __restrict__ bias,
    short* __restrict__ outS, int ostride, int ooff, int nxp) {
  __shared__ short As0[128 * 32], Bs0[128 * 32];
  __shared__ short As1[128 * 32], Bs1[128 * 32];
  // XCD-bijective remap: all 4 col-blocks of a panel share lin%8 (same XCD L2)
  const int lin = blockIdx.x;
  const int pnl = (lin & 7) + ((lin >> 5) << 3);
  const int cbk = (lin >> 3) & 3;
  if (pnl >= nxp) return;
  const int m0 = pnl * 128, n0 = cbk * 128;
  const int t = threadIdx.x;
  const int l = t & 63, wid = t >> 6;
  const int wr = (wid >> 1) * 64, wc = (wid & 1) * 64;
  const int fr = l & 15, fs = l >> 4;

  f32x4 acc[4][4];
#pragma unroll
  for (int a = 0; a < 4; ++a)
#pragma unroll
    for (int b = 0; b < 4; ++b) acc[a][b] = (f32x4){0.f, 0.f, 0.f, 0.f};

  // staging geometry (swizzled source -> linear LDS; idx = r*4 + phys_slot)
  const int idx0 = t, r0 = idx0 >> 2, sp0 = idx0 & 3;
  const int sl0 = (sp0 - (r0 >> 1)) & 3;
  const int idx1 = t + 256, r1 = idx1 >> 2, sp1 = idx1 & 3;
  const int sl1 = (sp1 - (r1 >> 1)) & 3;
  int rowA0 = m0 + r0; rowA0 = rowA0 < N_NODES ? rowA0 : N_NODES - 1;
  int rowA1 = m0 + r1; rowA1 = rowA1 < N_NODES ? rowA1 : N_NODES - 1;
  const short* Ap0 = A + (size_t)rowA0 * K + sl0 * 8;
  const short* Ap1 = A + (size_t)rowA1 * K + sl1 * 8;
  const short* Bp0 = B + (size_t)(n0 + r0) * K + sl0 * 8;
  const short* Bp1 = B + (size_t)(n0 + r1) * K + sl1 * 8;

#define STAGE(AS, BS, k0)                    \
  gload16(Ap0 + (k0), &AS[idx0 * 8]);        \
  gload16(Bp0 + (k0), &BS[idx0 * 8]);        \
  gload16(Ap1 + (k0), &AS[idx1 * 8]);        \
  gload16(Bp1 + (k0), &BS[idx1 * 8]);

#define COMPUTE(AS, BS) {                                                          \
  bf16x8 av[4], bv[4];                                                             \
  _Pragma("unroll")                                                                \
  for (int mi = 0; mi < 4; ++mi) {                                                 \
    const int r = wr + mi * 16 + fr;                                               \
    av[mi] = *reinterpret_cast<const bf16x8*>(&AS[r * 32 + ((fs + (r >> 1)) & 3) * 8]); \
  }                                                                                \
  _Pragma("unroll")                                                                \
  for (int ni = 0; ni < 4; ++ni) {                                                 \
    const int r = wc + ni * 16 + fr;                                               \
    bv[ni] = *reinterpret_cast<const bf16x8*>(&BS[r * 32 + ((fs + (r >> 1)) & 3) * 8]); \
  }                                                                                \
  _Pragma("unroll")                                                                \
  for (int mi = 0; mi < 4; ++mi)                                                   \
    _Pragma("unroll")                                                              \
    for (int ni = 0; ni < 4; ++ni)                                                 \
      acc[mi][ni] = __builtin_amdgcn_mfma_f32_16x16x32_bf16(av[mi], bv[ni],        \
                                                            acc[mi][ni], 0, 0, 0); }

  STAGE(As0, Bs0, 0);
  asm volatile("s_waitcnt vmcnt(0)" ::: "memory");
  __builtin_amdgcn_s_barrier();

  for (int k0 = 0; k0 < K; k0 += 64) {
    if (k0 + 32 < K) { STAGE(As1, Bs1, k0 + 32); }
    COMPUTE(As0, Bs0);
    asm volatile("s_waitcnt vmcnt(0)" ::: "memory");
    __builtin_amdgcn_s_barrier();
    if (k0 + 64 < K) { STAGE(As0, Bs0, k0 + 64); }
    COMPUTE(As1, Bs1);
    asm volatile("s_waitcnt vmcnt(0)" ::: "memory");
    __builtin_amdgcn_s_barrier();
  }
#undef STAGE
#undef COMPUTE

#pragma unroll
  for (int ni = 0; ni < 4; ++ni) {
    const int col = n0 + wc + ni * 16 + fr;
    const float bb = bias[col];
#pragma unroll
    for (int mi = 0; mi < 4; ++mi) {
      const f32x4 c = acc[mi][ni];
#pragma unroll
      for (int i = 0; i < 4; ++i) {
        const int row = m0 + wr + mi * 16 + fs * 4 + i;
        if (row < N_NODES) {
          float v = c[i] + bb;
          if (RELU) v = fmaxf(v, 0.f);
          outS[(size_t)row * ostride + ooff + col] = f2bf(v);
        }
      }
    }
  }
}

// ---------------- pool: GR[g] = mean over rows of bf16 X2 --------------------
__global__ __launch_bounds__(256) void k_pool(const short* __restrict__ X2b,
                                              const int* __restrict__ rstart,
                                              float* __restrict__ GR) {
  __shared__ float part[4][HD];
  const int g = blockIdx.x, t = threadIdx.x;
  const int gi = t >> 6, l = t & 63;
  const int s0 = rstart[g], s1 = rstart[g + 1];
  float acc[8] = {0.f, 0.f, 0.f, 0.f, 0.f, 0.f, 0.f, 0.f};
  for (int r = s0 + gi; r < s1; r += 4) {
    bf16x8 v = *reinterpret_cast<const bf16x8*>(&X2b[(size_t)r * HD + l * 8]);
#pragma unroll
    for (int j = 0; j < 8; ++j) acc[j] += bf2f(v[j]);
  }
#pragma unroll
  for (int j = 0; j < 8; ++j) part[gi][l * 8 + j] = acc[j];
  __syncthreads();
  const float inv = 1.0f / fmaxf((float)(s1 - s0), 1.0f);
  for (int c = t; c < HD; c += 256)
    GR[g * HD + c] = (part[0][c] + part[1][c] + part[2][c] + part[3][c]) * inv;
}

// ---------------- classifier MLP layer 1: h = relu(GR @ Wc1^T + bc1) ---------
__global__ __launch_bounds__(256) void k_mlp1(
    const float* __restrict__ GR, const float* __restrict__ Wc1T,
    const float* __restrict__ bc1, float* __restrict__ HS) {
  __shared__ float grs[HD];
  const int g = blockIdx.x;
  const int t = threadIdx.x;
  const int c = blockIdx.y * 256 + t;
  grs[t]       = GR[g * HD + t];
  grs[t + 256] = GR[g * HD + t + 256];
  __syncthreads();
  float acc = 0.f;
#pragma unroll 8
  for (int k = 0; k < HD; ++k)
    acc = fmaf(Wc1T[k * HD + c], grs[k], acc);
  HS[g * HD + c] = fmaxf(acc + bc1[c], 0.f);
}

// ---------------- classifier MLP layer 2: out = HS @ Wc2^T + bc2 -------------
__global__ __launch_bounds__(256) void k_mlp2(
    const float* __restrict__ HS, const float* __restrict__ Wc2T,
    const float* __restrict__ bc2, float* __restrict__ out) {
  __shared__ float hsm[HD];
  const int g = blockIdx.x;
  const int t = threadIdx.x;
  const int c = blockIdx.y * 256 + t;
  hsm[t]       = HS[g * HD + t];
  hsm[t + 256] = HS[g * HD + t + 256];
  __syncthreads();
  if (c < NTAC) {
    float acc = 0.f;
#pragma unroll 8
    for (int k = 0; k < HD; ++k)
      acc = fmaf(Wc2T[k * NTAC + c], hsm[k], acc);
    out[g * NTAC + c] = acc + bc2[c];
  }
}

extern "C" void kernel_launch(void* const* d_in, const int* in_sizes, int n_in,
                              void* d_out, int out_size, void* d_ws, size_t ws_size,
                              hipStream_t stream) {
  const int*   node_type = (const int*)d_in[0];
  const int*   node_tac  = (const int*)d_in[1];
  const int*   edge      = (const int*)d_in[2];
  const int*   batch     = (const int*)d_in[3];
  const float* temb      = (const float*)d_in[4];
  const float* tacemb    = (const float*)d_in[5];
  const float* W1l       = (const float*)d_in[6];
  const float* b1l       = (const float*)d_in[7];
  const float* W1r       = (const float*)d_in[8];
  const float* W2l       = (const float*)d_in[9];
  const float* b2l       = (const float*)d_in[10];
  const float* W2r       = (const float*)d_in[11];
  const float* Wc1       = (const float*)d_in[12];
  const float* bc1       = (const float*)d_in[13];
  const float* Wc2       = (const float*)d_in[14];
  const float* bc2       = (const float*)d_in[15];
  const int* src = edge;
  const int* dst = edge + N_EDGES;

  // ---- workspace layout ----
  char* p = (char*)d_ws;
  int*   DEG    = (int*)p;    p += N_NODES * 4;            // zeroed
  int*   CUR    = (int*)p;    p += N_NODES * 4;            // zeroed
  size_t zero_bytes = (size_t)(2 * N_NODES) * 4;
  int*   ROWS   = (int*)p;    p += (N_NODES + 4) * 4;
  int*   RSTART = (int*)p;    p += (NGRAPH + 4) * 4;
  int*   ESRC   = (int*)p;    p += N_EDGES * 4;
  short* A1     = (short*)p;  p += (size_t)N_NODES * 192 * 2;   // [agg1 | x]
  short* A2     = (short*)p;  p += (size_t)N_NODES * 1024 * 2;  // [agg2 | x1]
  short* X2B    = (short*)p;  p += (size_t)N_NODES * HD * 2;
  float* GR     = (float*)p;  p += NGRAPH * HD * 4;
  float* HS     = (float*)p;  p += NGRAPH * HD * 4;
  short* BC1    = (short*)p;  p += HD * 192 * 2;
  short* BC2    = (short*)p;  p += HD * 1024 * 2;
  float* WC1T   = (float*)p;  p += HD * HD * 4;
  float* WC2T   = (float*)p;  p += HD * NTAC * 4;

  hipMemsetAsync(d_ws, 0, zero_bytes, stream);

  // merged weight prep (transposes + bf16 concat-casts)
  const int prep_items = HD * HD + NTAC * HD + HD * 192 / 4 + HD * 1024 / 4;
  k_prep<<<(prep_items + 255) / 256, 256, 0, stream>>>(Wc1, Wc2, WC1T, WC2T,
                                                       W1l, W1r, BC1, W2l, W2r, BC2);

  // CSR + graph bounds
  k_degree<<<N_EDGES / 256, 256, 0, stream>>>(dst, DEG);
  k_scan<<<1, 1024, 0, stream>>>(DEG, ROWS);
  k_scatter<<<N_EDGES / 256, 256, 0, stream>>>(src, dst, ROWS, CUR, ESRC);
  k_gbounds<<<(N_NODES + 255) / 256, 256, 0, stream>>>(batch, RSTART);

  // forward
  k_embed<<<(N_NODES * 24) / 256, 256, 0, stream>>>(node_type, node_tac, temb, tacemb, A1);
  k_gather96<<<(N_NODES * 24) / 256, 256, 0, stream>>>(ROWS, ESRC, A1);
  const int NXP = (N_NODES + 127) / 128;          // 157 row panels
  const int GEMM_BLOCKS = 640;                    // 160 panels x 4, bijective swizzle
  k_gemm<192, true><<<GEMM_BLOCKS, 256, 0, stream>>>(A1, BC1, b1l, A2, 1024, 512, NXP);
  k_gather512<<<(N_NODES * 64) / 256, 256, 0, stream>>>(ROWS, ESRC, A2);
  k_gemm<1024, false><<<GEMM_BLOCKS, 256, 0, stream>>>(A2, BC2, b2l, X2B, 512, 0, NXP);
  k_pool<<<NGRAPH, 256, 0, stream>>>(X2B, RSTART, GR);
  k_mlp1<<<dim3(NGRAPH, 2), 256, 0, stream>>>(GR, WC1T, bc1, HS);
  k_mlp2<<<dim3(NGRAPH, 4), 256, 0, stream>>>(HS, WC2T, bc2, (float*)d_out);
}

// Round 6
// 270.054 us; speedup vs baseline: 12.7867x; 1.0703x over previous
//
#include <hip/hip_runtime.h>

#define N_NODES 20000
#define N_EDGES 320000
#define NGRAPH  256
#define NTAC    1000
#define HD      512

typedef __attribute__((ext_vector_type(8))) short bf16x8;
typedef __attribute__((ext_vector_type(4))) short short4v;
typedef __attribute__((ext_vector_type(4))) float f32x4;

__device__ __forceinline__ short f2bf(float f) {      // RNE float->bf16
  union { float f; unsigned u; } v; v.f = f;
  unsigned r = v.u + 0x7FFFu + ((v.u >> 16) & 1u);
  return (short)(r >> 16);
}
__device__ __forceinline__ float bf2f(short s) {
  union { unsigned u; float f; } v;
  v.u = ((unsigned)(unsigned short)s) << 16;
  return v.f;
}
__device__ __forceinline__ bf16x8 cast8(const float* p) {
  float4 v0 = *reinterpret_cast<const float4*>(p);
  float4 v1 = *reinterpret_cast<const float4*>(p + 4);
  bf16x8 o;
  o[0] = f2bf(v0.x); o[1] = f2bf(v0.y); o[2] = f2bf(v0.z); o[3] = f2bf(v0.w);
  o[4] = f2bf(v1.x); o[5] = f2bf(v1.y); o[6] = f2bf(v1.z); o[7] = f2bf(v1.w);
  return o;
}
__device__ __forceinline__ void gload16(const void* g, void* l) {
  __builtin_amdgcn_global_load_lds((const __attribute__((address_space(1))) void*)g,
                                   (__attribute__((address_space(3))) void*)l,
                                   16, 0, 0);
}

// ---------------- fused front: weight casts + embed + degree + gbounds --------
__global__ void k_front(const float* __restrict__ Wc1, const float* __restrict__ Wc2,
                        short* __restrict__ WC1B, short* __restrict__ WC2B,
                        const float* __restrict__ W1l, const float* __restrict__ W1r,
                        short* __restrict__ BC1,
                        const float* __restrict__ W2l, const float* __restrict__ W2r,
                        short* __restrict__ BC2,
                        const int* __restrict__ ntype, const int* __restrict__ ntac,
                        const float* __restrict__ temb, const float* __restrict__ tacemb,
                        short* __restrict__ A1,
                        const int* __restrict__ dst, int* __restrict__ deg,
                        const int* __restrict__ batch, int* __restrict__ rstart) {
  int idx = blockIdx.x * 256 + threadIdx.x;
  const int S0 = HD * HD / 8;        // Wc1 cast (oct)
  const int S1 = NTAC * HD / 8;      // Wc2 cast (oct)
  const int S2 = HD * 192 / 8;       // BC1 (oct)
  const int S3 = HD * 1024 / 8;      // BC2 (oct)
  const int S4 = N_NODES * 24;       // embed
  const int S5 = N_EDGES;            // degree
  const int S6 = N_NODES;            // gbounds
  if (idx < S0) {
    *reinterpret_cast<bf16x8*>(&WC1B[idx * 8]) = cast8(&Wc1[idx * 8]);
  } else if ((idx -= S0) < S1) {
    *reinterpret_cast<bf16x8*>(&WC2B[idx * 8]) = cast8(&Wc2[idx * 8]);
  } else if ((idx -= S1) < S2) {
    int n = idx / 24, k8 = idx - n * 24;
    const float* s = (k8 < 12) ? &W1l[(size_t)n * 96 + k8 * 8]
                               : &W1r[(size_t)n * 96 + (k8 - 12) * 8];
    *reinterpret_cast<bf16x8*>(&BC1[(size_t)n * 192 + k8 * 8]) = cast8(s);
  } else if ((idx -= S2) < S3) {
    int n = idx >> 7, k8 = idx & 127;
    const float* s = (k8 < 64) ? &W2l[(size_t)n * 512 + k8 * 8]
                               : &W2r[(size_t)n * 512 + (k8 - 64) * 8];
    *reinterpret_cast<bf16x8*>(&BC2[(size_t)n * 1024 + k8 * 8]) = cast8(s);
  } else if ((idx -= S3) < S4) {
    int node = idx / 24;
    int j = idx - node * 24;
    float4 v;
    int col;
    if (j < 8) {
      int t = ntype[node];
      v = *reinterpret_cast<const float4*>(&temb[t * 32 + j * 4]);
      col = j * 4;
    } else {
      int s = ntac[node] + 1;
      s = s < 0 ? 0 : (s > NTAC ? NTAC : s);
      v = *reinterpret_cast<const float4*>(&tacemb[s * 64 + (j - 8) * 4]);
      col = 32 + (j - 8) * 4;
    }
    short4v o = {f2bf(v.x), f2bf(v.y), f2bf(v.z), f2bf(v.w)};
    *reinterpret_cast<short4v*>(&A1[(size_t)node * 192 + 96 + col]) = o;
  } else if ((idx -= S4) < S5) {
    atomicAdd(&deg[dst[idx]], 1);
  } else if ((idx -= S5) < S6) {
    int i = idx;
    int b = batch[i];
    int bp = (i == 0) ? -1 : batch[i - 1];
    for (int g = bp + 1; g <= b; ++g) rstart[g] = i;
    if (i == N_NODES - 1)
      for (int g = b + 1; g <= NGRAPH; ++g) rstart[g] = N_NODES;
  }
}

// ---------------- CSR build: exclusive scan ----------------
__global__ __launch_bounds__(1024) void k_scan(const int* __restrict__ deg,
                                               int* __restrict__ rowstart) {
  __shared__ int partial[1024];
  const int t = threadIdx.x;
  const int CH = (N_NODES + 1023) / 1024;  // 20
  int s = 0;
  for (int i = 0; i < CH; ++i) {
    int idx = t * CH + i;
    if (idx < N_NODES) s += deg[idx];
  }
  partial[t] = s;
  __syncthreads();
  for (int off = 1; off < 1024; off <<= 1) {
    int v = (t >= off) ? partial[t - off] : 0;
    __syncthreads();
    partial[t] += v;
    __syncthreads();
  }
  int run = (t == 0) ? 0 : partial[t - 1];
  for (int i = 0; i < CH; ++i) {
    int idx = t * CH + i;
    if (idx < N_NODES) { rowstart[idx] = run; run += deg[idx]; }
  }
  if (t == 1023) rowstart[N_NODES] = run;
}

__global__ void k_scatter(const int* __restrict__ src, const int* __restrict__ dst,
                          const int* __restrict__ rowstart, int* __restrict__ cur,
                          int* __restrict__ esrc) {
  int e = blockIdx.x * 256 + threadIdx.x;
  if (e < N_EDGES) {
    int d = dst[e];
    int p = rowstart[d] + atomicAdd(&cur[d], 1);
    esrc[p] = src[e];
  }
}

// ---------------- gather-mean D=96: A1[:,0:96] = mean nbr A1[:,96:192] --------
__global__ __launch_bounds__(256) void k_gather96(
    const int* __restrict__ rowstart, const int* __restrict__ esrc,
    short* __restrict__ A1) {
  int tid = blockIdx.x * 256 + threadIdx.x;
  int node = tid / 24;
  int c = (tid - node * 24) * 4;
  if (node >= N_NODES) return;
  const int s0 = rowstart[node], s1 = rowstart[node + 1];
  float a0 = 0.f, a1 = 0.f, a2 = 0.f, a3 = 0.f;
  for (int i = s0; i < s1; ++i) {
    int nbr = esrc[i];
    short4v v = *reinterpret_cast<const short4v*>(&A1[(size_t)nbr * 192 + 96 + c]);
    a0 += bf2f(v[0]); a1 += bf2f(v[1]); a2 += bf2f(v[2]); a3 += bf2f(v[3]);
  }
  const float inv = 1.0f / fmaxf((float)(s1 - s0), 1.0f);
  short4v o = {f2bf(a0 * inv), f2bf(a1 * inv), f2bf(a2 * inv), f2bf(a3 * inv)};
  *reinterpret_cast<short4v*>(&A1[(size_t)node * 192 + c]) = o;
}

// ---------------- gather-mean D=512: A2[:,0:512] = mean nbr A2[:,512:1024] ----
__global__ __launch_bounds__(256) void k_gather512(
    const int* __restrict__ rowstart, const int* __restrict__ esrc,
    short* __restrict__ A2) {
  int tid = blockIdx.x * 256 + threadIdx.x;
  int node = tid >> 6;
  int c = (tid & 63) << 3;
  const int s0 = rowstart[node], s1 = rowstart[node + 1];
  float acc0[8] = {0.f, 0.f, 0.f, 0.f, 0.f, 0.f, 0.f, 0.f};
  float acc1[8] = {0.f, 0.f, 0.f, 0.f, 0.f, 0.f, 0.f, 0.f};
  int i = s0;
  for (; i + 2 <= s1; i += 2) {
    int nbr0 = esrc[i], nbr1 = esrc[i + 1];
    bf16x8 v0 = *reinterpret_cast<const bf16x8*>(&A2[(size_t)nbr0 * 1024 + 512 + c]);
    bf16x8 v1 = *reinterpret_cast<const bf16x8*>(&A2[(size_t)nbr1 * 1024 + 512 + c]);
#pragma unroll
    for (int j = 0; j < 8; ++j) { acc0[j] += bf2f(v0[j]); acc1[j] += bf2f(v1[j]); }
  }
  if (i < s1) {
    int nbr = esrc[i];
    bf16x8 v = *reinterpret_cast<const bf16x8*>(&A2[(size_t)nbr * 1024 + 512 + c]);
#pragma unroll
    for (int j = 0; j < 8; ++j) acc0[j] += bf2f(v[j]);
  }
  const float inv = 1.0f / fmaxf((float)(s1 - s0), 1.0f);
  bf16x8 o;
#pragma unroll
  for (int j = 0; j < 8; ++j) o[j] = f2bf((acc0[j] + acc1[j]) * inv);
  *reinterpret_cast<bf16x8*>(&A2[(size_t)node * 1024 + c]) = o;
}

// ---------------- bf16 MFMA GEMM, 3-buffer counted-vmcnt pipeline, XCD-swz ----
// C[M,512] = A[M,K] @ B[512,K]^T + bias; optional RELU; store bf16.
template<int K, bool RELU>
__global__ __launch_bounds__(256) void k_gemm(
    const short* __restrict__ A, const short* __restrict__ B,
    const float* __restrict__ bias,
    short* __restrict__ outS, int ostride, int ooff, int nxp) {
  __shared__ short As0[4096], Bs0[4096];
  __shared__ short As1[4096], Bs1[4096];
  __shared__ short As2[4096], Bs2[4096];   // 48 KB total -> 3 blocks/CU
  // XCD-bijective remap: all 4 col-blocks of a panel share lin%8 (same XCD L2)
  const int lin = blockIdx.x;
  const int pnl = (lin & 7) + ((lin >> 5) << 3);
  const int cbk = (lin >> 3) & 3;
  if (pnl >= nxp) return;
  const int m0 = pnl * 128, n0 = cbk * 128;
  const int t = threadIdx.x;
  const int l = t & 63, wid = t >> 6;
  const int wr = (wid >> 1) * 64, wc = (wid & 1) * 64;
  const int fr = l & 15, fs = l >> 4;

  f32x4 acc[4][4];
#pragma unroll
  for (int a = 0; a < 4; ++a)
#pragma unroll
    for (int b = 0; b < 4; ++b) acc[a][b] = (f32x4){0.f, 0.f, 0.f, 0.f};

  // staging geometry (swizzled source -> linear LDS; idx = r*4 + phys_slot)
  const int idx0 = t, r0 = idx0 >> 2, sp0 = idx0 & 3;
  const int sl0 = (sp0 - (r0 >> 1)) & 3;
  const int idx1 = t + 256, r1 = idx1 >> 2, sp1 = idx1 & 3;
  const int sl1 = (sp1 - (r1 >> 1)) & 3;
  int rowA0 = m0 + r0; rowA0 = rowA0 < N_NODES ? rowA0 : N_NODES - 1;
  int rowA1 = m0 + r1; rowA1 = rowA1 < N_NODES ? rowA1 : N_NODES - 1;
  const short* Ap0 = A + (size_t)rowA0 * K + sl0 * 8;
  const short* Ap1 = A + (size_t)rowA1 * K + sl1 * 8;
  const short* Bp0 = B + (size_t)(n0 + r0) * K + sl0 * 8;
  const short* Bp1 = B + (size_t)(n0 + r1) * K + sl1 * 8;

  constexpr int NK = K / 32;

#define STAGE(AS, BS, k0)                    \
  gload16(Ap0 + (k0), &AS[idx0 * 8]);        \
  gload16(Bp0 + (k0), &BS[idx0 * 8]);        \
  gload16(Ap1 + (k0), &AS[idx1 * 8]);        \
  gload16(Bp1 + (k0), &BS[idx1 * 8]);

#define COMPUTE(AS, BS) {                                                          \
  bf16x8 av[4], bv[4];                                                             \
  _Pragma("unroll")                                                                \
  for (int mi = 0; mi < 4; ++mi) {                                                 \
    const int r = wr + mi * 16 + fr;                                               \
    av[mi] = *reinterpret_cast<const bf16x8*>(&AS[r * 32 + ((fs + (r >> 1)) & 3) * 8]); \
  }                                                                                \
  _Pragma("unroll")                                                                \
  for (int ni = 0; ni < 4; ++ni) {                                                 \
    const int r = wc + ni * 16 + fr;                                               \
    bv[ni] = *reinterpret_cast<const bf16x8*>(&BS[r * 32 + ((fs + (r >> 1)) & 3) * 8]); \
  }                                                                                \
  _Pragma("unroll")                                                                \
  for (int mi = 0; mi < 4; ++mi)                                                   \
    _Pragma("unroll")                                                              \
    for (int ni = 0; ni < 4; ++ni)                                                 \
      acc[mi][ni] = __builtin_amdgcn_mfma_f32_16x16x32_bf16(av[mi], bv[ni],        \
                                                            acc[mi][ni], 0, 0, 0); }

  // Per phase k: wait own stage-k loads (leave stage-k+1 in flight: vmcnt(4)),
  // barrier (=> all waves' stage-k in LDS, all waves done compute(k-1)),
  // stage k+2 into the buffer freed by compute(k-1), then compute(k).
#define PHASE(k, CA, CB, SA, SB)                                                 \
  if ((k) + 1 < NK) { asm volatile("s_waitcnt vmcnt(4)" ::: "memory"); }         \
  else              { asm volatile("s_waitcnt vmcnt(0)" ::: "memory"); }         \
  __builtin_amdgcn_s_barrier();                                                  \
  if ((k) + 2 < NK) { STAGE(SA, SB, ((k) + 2) * 32) }                            \
  COMPUTE(CA, CB)

  STAGE(As0, Bs0, 0)
  STAGE(As1, Bs1, 32)
#pragma unroll
  for (int kk = 0; kk < NK; kk += 3) {
    PHASE(kk, As0, Bs0, As2, Bs2)
    if (kk + 1 < NK) { PHASE(kk + 1, As1, Bs1, As0, Bs0) }
    if (kk + 2 < NK) { PHASE(kk + 2, As2, Bs2, As1, Bs1) }
  }
#undef PHASE
#undef STAGE
#undef COMPUTE

#pragma unroll
  for (int ni = 0; ni < 4; ++ni) {
    const int col = n0 + wc + ni * 16 + fr;
    const float bb = bias[col];
#pragma unroll
    for (int mi = 0; mi < 4; ++mi) {
      const f32x4 c = acc[mi][ni];
#pragma unroll
      for (int i = 0; i < 4; ++i) {
        const int row = m0 + wr + mi * 16 + fs * 4 + i;
        if (row < N_NODES) {
          float v = c[i] + bb;
          if (RELU) v = fmaxf(v, 0.f);
          outS[(size_t)row * ostride + ooff + col] = f2bf(v);
        }
      }
    }
  }
}

// ---------------- pool: GR[g] = mean over rows of bf16 X2 --------------------
__global__ __launch_bounds__(256) void k_pool(const short* __restrict__ X2b,
                                              const int* __restrict__ rstart,
                                              float* __restrict__ GR) {
  __shared__ float part[4][HD];
  const int g = blockIdx.x, t = threadIdx.x;
  const int gi = t >> 6, l = t & 63;
  const int s0 = rstart[g], s1 = rstart[g + 1];
  float acc[8] = {0.f, 0.f, 0.f, 0.f, 0.f, 0.f, 0.f, 0.f};
  for (int r = s0 + gi; r < s1; r += 4) {
    bf16x8 v = *reinterpret_cast<const bf16x8*>(&X2b[(size_t)r * HD + l * 8]);
#pragma unroll
    for (int j = 0; j < 8; ++j) acc[j] += bf2f(v[j]);
  }
#pragma unroll
  for (int j = 0; j < 8; ++j) part[gi][l * 8 + j] = acc[j];
  __syncthreads();
  const float inv = 1.0f / fmaxf((float)(s1 - s0), 1.0f);
  for (int c = t; c < HD; c += 256)
    GR[g * HD + c] = (part[0][c] + part[1][c] + part[2][c] + part[3][c]) * inv;
}

// ---------------- classifier MLP1: h = relu(GR @ Wc1^T + bc1), bf16 weights ---
// grid (NGRAPH/4, 2): 4 graphs/block, 256 cols/block; Wc1B row-major [512][512]
__global__ __launch_bounds__(256) void k_mlp1(
    const float* __restrict__ GR, const short* __restrict__ Wc1B,
    const float* __restrict__ bc1, float* __restrict__ HS) {
  __shared__ float grs[4][HD];
  const int g0 = blockIdx.x * 4, t = threadIdx.x;
  for (int f = t; f < 4 * HD / 4; f += 256) {
    int r = f >> 7, c = (f & 127) << 2;
    *reinterpret_cast<float4*>(&grs[r][c]) =
        *reinterpret_cast<const float4*>(&GR[(size_t)(g0 + r) * HD + c]);
  }
  __syncthreads();
  const int c = blockIdx.y * 256 + t;
  const short* wrow = &Wc1B[(size_t)c * HD];
  float a0 = 0.f, a1 = 0.f, a2 = 0.f, a3 = 0.f;
#pragma unroll 8
  for (int k8 = 0; k8 < HD / 8; ++k8) {
    bf16x8 w = *reinterpret_cast<const bf16x8*>(&wrow[k8 * 8]);
#pragma unroll
    for (int j = 0; j < 8; ++j) {
      const float wv = bf2f(w[j]);
      const int k = k8 * 8 + j;
      a0 = fmaf(wv, grs[0][k], a0);
      a1 = fmaf(wv, grs[1][k], a1);
      a2 = fmaf(wv, grs[2][k], a2);
      a3 = fmaf(wv, grs[3][k], a3);
    }
  }
  const float bb = bc1[c];
  HS[(size_t)(g0 + 0) * HD + c] = fmaxf(a0 + bb, 0.f);
  HS[(size_t)(g0 + 1) * HD + c] = fmaxf(a1 + bb, 0.f);
  HS[(size_t)(g0 + 2) * HD + c] = fmaxf(a2 + bb, 0.f);
  HS[(size_t)(g0 + 3) * HD + c] = fmaxf(a3 + bb, 0.f);
}

// ---------------- classifier MLP2: out = HS @ Wc2^T + bc2, bf16 weights ------
// grid (NGRAPH/4, 4): 4 graphs/block, 256 cols/block; Wc2B row-major [1000][512]
__global__ __launch_bounds__(256) void k_mlp2(
    const float* __restrict__ HS, const short* __restrict__ Wc2B,
    const float* __restrict__ bc2, float* __restrict__ out) {
  __shared__ float hsm[4][HD];
  const int g0 = blockIdx.x * 4, t = threadIdx.x;
  for (int f = t; f < 4 * HD / 4; f += 256) {
    int r = f >> 7, c = (f & 127) << 2;
    *reinterpret_cast<float4*>(&hsm[r][c]) =
        *reinterpret_cast<const float4*>(&HS[(size_t)(g0 + r) * HD + c]);
  }
  __syncthreads();
  const int c = blockIdx.y * 256 + t;
  if (c >= NTAC) return;
  const short* wrow = &Wc2B[(size_t)c * HD];
  float a0 = 0.f, a1 = 0.f, a2 = 0.f, a3 = 0.f;
#pragma unroll 8
  for (int k8 = 0; k8 < HD / 8; ++k8) {
    bf16x8 w = *reinterpret_cast<const bf16x8*>(&wrow[k8 * 8]);
#pragma unroll
    for (int j = 0; j < 8; ++j) {
      const float wv = bf2f(w[j]);
      const int k = k8 * 8 + j;
      a0 = fmaf(wv, hsm[0][k], a0);
      a1 = fmaf(wv, hsm[1][k], a1);
      a2 = fmaf(wv, hsm[2][k], a2);
      a3 = fmaf(wv, hsm[3][k], a3);
    }
  }
  const float bb = bc2[c];
  out[(size_t)(g0 + 0) * NTAC + c] = a0 + bb;
  out[(size_t)(g0 + 1) * NTAC + c] = a1 + bb;
  out[(size_t)(g0 + 2) * NTAC + c] = a2 + bb;
  out[(size_t)(g0 + 3) * NTAC + c] = a3 + bb;
}

extern "C" void kernel_launch(void* const* d_in, const int* in_sizes, int n_in,
                              void* d_out, int out_size, void* d_ws, size_t ws_size,
                              hipStream_t stream) {
  const int*   node_type = (const int*)d_in[0];
  const int*   node_tac  = (const int*)d_in[1];
  const int*   edge      = (const int*)d_in[2];
  const int*   batch     = (const int*)d_in[3];
  const float* temb      = (const float*)d_in[4];
  const float* tacemb    = (const float*)d_in[5];
  const float* W1l       = (const float*)d_in[6];
  const float* b1l       = (const float*)d_in[7];
  const float* W1r       = (const float*)d_in[8];
  const float* W2l       = (const float*)d_in[9];
  const float* b2l       = (const float*)d_in[10];
  const float* W2r       = (const float*)d_in[11];
  const float* Wc1       = (const float*)d_in[12];
  const float* bc1       = (const float*)d_in[13];
  const float* Wc2       = (const float*)d_in[14];
  const float* bc2       = (const float*)d_in[15];
  const int* src = edge;
  const int* dst = edge + N_EDGES;

  // ---- workspace layout ----
  char* p = (char*)d_ws;
  int*   DEG    = (int*)p;    p += N_NODES * 4;            // zeroed
  int*   CUR    = (int*)p;    p += N_NODES * 4;            // zeroed
  size_t zero_bytes = (size_t)(2 * N_NODES) * 4;
  int*   ROWS   = (int*)p;    p += (N_NODES + 4) * 4;
  int*   RSTART = (int*)p;    p += (NGRAPH + 4) * 4;
  int*   ESRC   = (int*)p;    p += N_EDGES * 4;
  short* A1     = (short*)p;  p += (size_t)N_NODES * 192 * 2;   // [agg1 | x]
  short* A2     = (short*)p;  p += (size_t)N_NODES * 1024 * 2;  // [agg2 | x1]
  short* X2B    = (short*)p;  p += (size_t)N_NODES * HD * 2;
  float* GR     = (float*)p;  p += NGRAPH * HD * 4;
  float* HS     = (float*)p;  p += NGRAPH * HD * 4;
  short* BC1    = (short*)p;  p += HD * 192 * 2;
  short* BC2    = (short*)p;  p += HD * 1024 * 2;
  short* WC1B   = (short*)p;  p += HD * HD * 2;
  short* WC2B   = (short*)p;  p += (size_t)NTAC * HD * 2;

  hipMemsetAsync(d_ws, 0, zero_bytes, stream);

  // fused prologue: weight casts + embedding + degree histogram + graph bounds
  const int front_items = HD * HD / 8 + NTAC * HD / 8 + HD * 192 / 8 +
                          HD * 1024 / 8 + N_NODES * 24 + N_EDGES + N_NODES;
  k_front<<<(front_items + 255) / 256, 256, 0, stream>>>(
      Wc1, Wc2, WC1B, WC2B, W1l, W1r, BC1, W2l, W2r, BC2,
      node_type, node_tac, temb, tacemb, A1, dst, DEG, batch, RSTART);

  k_scan<<<1, 1024, 0, stream>>>(DEG, ROWS);
  k_scatter<<<N_EDGES / 256, 256, 0, stream>>>(src, dst, ROWS, CUR, ESRC);

  k_gather96<<<(N_NODES * 24) / 256, 256, 0, stream>>>(ROWS, ESRC, A1);
  const int NXP = (N_NODES + 127) / 128;          // 157 row panels
  const int GEMM_BLOCKS = 640;                    // 160 panels x 4, bijective swizzle
  k_gemm<192, true><<<GEMM_BLOCKS, 256, 0, stream>>>(A1, BC1, b1l, A2, 1024, 512, NXP);
  k_gather512<<<(N_NODES * 64) / 256, 256, 0, stream>>>(ROWS, ESRC, A2);
  k_gemm<1024, false><<<GEMM_BLOCKS, 256, 0, stream>>>(A2, BC2, b2l, X2B, 512, 0, NXP);
  k_pool<<<NGRAPH, 256, 0, stream>>>(X2B, RSTART, GR);
  k_mlp1<<<dim3(NGRAPH / 4, 2), 256, 0, stream>>>(GR, WC1B, bc1, HS);
  k_mlp2<<<dim3(NGRAPH / 4, 4), 256, 0, stream>>>(HS, WC2B, bc2, (float*)d_out);
}

// Round 7
// 258.066 us; speedup vs baseline: 13.3807x; 1.0465x over previous
//
#include <hip/hip_runtime.h>

#define N_NODES 20000
#define N_EDGES 320000
#define NGRAPH  256
#define NTAC    1000
#define HD      512

typedef __attribute__((ext_vector_type(8))) short bf16x8;
typedef __attribute__((ext_vector_type(4))) short short4v;
typedef __attribute__((ext_vector_type(4))) float f32x4;

__device__ __forceinline__ short f2bf(float f) {      // RNE float->bf16
  union { float f; unsigned u; } v; v.f = f;
  unsigned r = v.u + 0x7FFFu + ((v.u >> 16) & 1u);
  return (short)(r >> 16);
}
__device__ __forceinline__ float bf2f(short s) {
  union { unsigned u; float f; } v;
  v.u = ((unsigned)(unsigned short)s) << 16;
  return v.f;
}
__device__ __forceinline__ bf16x8 cast8(const float* p) {
  float4 v0 = *reinterpret_cast<const float4*>(p);
  float4 v1 = *reinterpret_cast<const float4*>(p + 4);
  bf16x8 o;
  o[0] = f2bf(v0.x); o[1] = f2bf(v0.y); o[2] = f2bf(v0.z); o[3] = f2bf(v0.w);
  o[4] = f2bf(v1.x); o[5] = f2bf(v1.y); o[6] = f2bf(v1.z); o[7] = f2bf(v1.w);
  return o;
}
__device__ __forceinline__ void gload16(const void* g, void* l) {
  __builtin_amdgcn_global_load_lds((const __attribute__((address_space(1))) void*)g,
                                   (__attribute__((address_space(3))) void*)l,
                                   16, 0, 0);
}

// ---------------- fused front: weight casts + embed + degree + gbounds --------
__global__ void k_front(const float* __restrict__ Wc1, const float* __restrict__ Wc2,
                        short* __restrict__ WC1B, short* __restrict__ WC2B,
                        const float* __restrict__ W1l, const float* __restrict__ W1r,
                        short* __restrict__ BC1,
                        const float* __restrict__ W2l, const float* __restrict__ W2r,
                        short* __restrict__ BC2,
                        const int* __restrict__ ntype, const int* __restrict__ ntac,
                        const float* __restrict__ temb, const float* __restrict__ tacemb,
                        short* __restrict__ A1,
                        const int* __restrict__ dst, int* __restrict__ deg,
                        const int* __restrict__ batch, int* __restrict__ rstart) {
  int idx = blockIdx.x * 256 + threadIdx.x;
  const int S0 = HD * HD / 8;        // Wc1 cast (oct)
  const int S1 = NTAC * HD / 8;      // Wc2 cast (oct)
  const int S2 = HD * 192 / 8;       // BC1 (oct)
  const int S3 = HD * 1024 / 8;      // BC2 (oct)
  const int S4 = N_NODES * 24;       // embed
  const int S5 = N_EDGES;            // degree
  const int S6 = N_NODES;            // gbounds
  if (idx < S0) {
    *reinterpret_cast<bf16x8*>(&WC1B[idx * 8]) = cast8(&Wc1[idx * 8]);
  } else if ((idx -= S0) < S1) {
    *reinterpret_cast<bf16x8*>(&WC2B[idx * 8]) = cast8(&Wc2[idx * 8]);
  } else if ((idx -= S1) < S2) {
    int n = idx / 24, k8 = idx - n * 24;
    const float* s = (k8 < 12) ? &W1l[(size_t)n * 96 + k8 * 8]
                               : &W1r[(size_t)n * 96 + (k8 - 12) * 8];
    *reinterpret_cast<bf16x8*>(&BC1[(size_t)n * 192 + k8 * 8]) = cast8(s);
  } else if ((idx -= S2) < S3) {
    int n = idx >> 7, k8 = idx & 127;
    const float* s = (k8 < 64) ? &W2l[(size_t)n * 512 + k8 * 8]
                               : &W2r[(size_t)n * 512 + (k8 - 64) * 8];
    *reinterpret_cast<bf16x8*>(&BC2[(size_t)n * 1024 + k8 * 8]) = cast8(s);
  } else if ((idx -= S3) < S4) {
    int node = idx / 24;
    int j = idx - node * 24;
    float4 v;
    int col;
    if (j < 8) {
      int t = ntype[node];
      v = *reinterpret_cast<const float4*>(&temb[t * 32 + j * 4]);
      col = j * 4;
    } else {
      int s = ntac[node] + 1;
      s = s < 0 ? 0 : (s > NTAC ? NTAC : s);
      v = *reinterpret_cast<const float4*>(&tacemb[s * 64 + (j - 8) * 4]);
      col = 32 + (j - 8) * 4;
    }
    short4v o = {f2bf(v.x), f2bf(v.y), f2bf(v.z), f2bf(v.w)};
    *reinterpret_cast<short4v*>(&A1[(size_t)node * 192 + 96 + col]) = o;
  } else if ((idx -= S4) < S5) {
    atomicAdd(&deg[dst[idx]], 1);
  } else if ((idx -= S5) < S6) {
    int i = idx;
    int b = batch[i];
    int bp = (i == 0) ? -1 : batch[i - 1];
    for (int g = bp + 1; g <= b; ++g) rstart[g] = i;
    if (i == N_NODES - 1)
      for (int g = b + 1; g <= NGRAPH; ++g) rstart[g] = N_NODES;
  }
}

// ---------------- CSR build: exclusive scan ----------------
__global__ __launch_bounds__(1024) void k_scan(const int* __restrict__ deg,
                                               int* __restrict__ rowstart) {
  __shared__ int partial[1024];
  const int t = threadIdx.x;
  const int CH = (N_NODES + 1023) / 1024;  // 20
  int s = 0;
  for (int i = 0; i < CH; ++i) {
    int idx = t * CH + i;
    if (idx < N_NODES) s += deg[idx];
  }
  partial[t] = s;
  __syncthreads();
  for (int off = 1; off < 1024; off <<= 1) {
    int v = (t >= off) ? partial[t - off] : 0;
    __syncthreads();
    partial[t] += v;
    __syncthreads();
  }
  int run = (t == 0) ? 0 : partial[t - 1];
  for (int i = 0; i < CH; ++i) {
    int idx = t * CH + i;
    if (idx < N_NODES) { rowstart[idx] = run; run += deg[idx]; }
  }
  if (t == 1023) rowstart[N_NODES] = run;
}

__global__ void k_scatter(const int* __restrict__ src, const int* __restrict__ dst,
                          const int* __restrict__ rowstart, int* __restrict__ cur,
                          int* __restrict__ esrc) {
  int e = blockIdx.x * 256 + threadIdx.x;
  if (e < N_EDGES) {
    int d = dst[e];
    int p = rowstart[d] + atomicAdd(&cur[d], 1);
    esrc[p] = src[e];
  }
}

// ---------------- gather-mean D=96: A1[:,0:96] = mean nbr A1[:,96:192] --------
__global__ __launch_bounds__(256) void k_gather96(
    const int* __restrict__ rowstart, const int* __restrict__ esrc,
    short* __restrict__ A1) {
  int tid = blockIdx.x * 256 + threadIdx.x;
  int node = tid / 24;
  int c = (tid - node * 24) * 4;
  if (node >= N_NODES) return;
  const int s0 = rowstart[node], s1 = rowstart[node + 1];
  float a0 = 0.f, a1 = 0.f, a2 = 0.f, a3 = 0.f;
  for (int i = s0; i < s1; ++i) {
    int nbr = esrc[i];
    short4v v = *reinterpret_cast<const short4v*>(&A1[(size_t)nbr * 192 + 96 + c]);
    a0 += bf2f(v[0]); a1 += bf2f(v[1]); a2 += bf2f(v[2]); a3 += bf2f(v[3]);
  }
  const float inv = 1.0f / fmaxf((float)(s1 - s0), 1.0f);
  short4v o = {f2bf(a0 * inv), f2bf(a1 * inv), f2bf(a2 * inv), f2bf(a3 * inv)};
  *reinterpret_cast<short4v*>(&A1[(size_t)node * 192 + c]) = o;
}

// ---------------- gather-mean D=512: A2[:,0:512] = mean nbr A2[:,512:1024] ----
__global__ __launch_bounds__(256) void k_gather512(
    const int* __restrict__ rowstart, const int* __restrict__ esrc,
    short* __restrict__ A2) {
  int tid = blockIdx.x * 256 + threadIdx.x;
  int node = tid >> 6;
  int c = (tid & 63) << 3;
  const int s0 = rowstart[node], s1 = rowstart[node + 1];
  float acc0[8] = {0.f, 0.f, 0.f, 0.f, 0.f, 0.f, 0.f, 0.f};
  float acc1[8] = {0.f, 0.f, 0.f, 0.f, 0.f, 0.f, 0.f, 0.f};
  int i = s0;
  for (; i + 2 <= s1; i += 2) {
    int nbr0 = esrc[i], nbr1 = esrc[i + 1];
    bf16x8 v0 = *reinterpret_cast<const bf16x8*>(&A2[(size_t)nbr0 * 1024 + 512 + c]);
    bf16x8 v1 = *reinterpret_cast<const bf16x8*>(&A2[(size_t)nbr1 * 1024 + 512 + c]);
#pragma unroll
    for (int j = 0; j < 8; ++j) { acc0[j] += bf2f(v0[j]); acc1[j] += bf2f(v1[j]); }
  }
  if (i < s1) {
    int nbr = esrc[i];
    bf16x8 v = *reinterpret_cast<const bf16x8*>(&A2[(size_t)nbr * 1024 + 512 + c]);
#pragma unroll
    for (int j = 0; j < 8; ++j) acc0[j] += bf2f(v[j]);
  }
  const float inv = 1.0f / fmaxf((float)(s1 - s0), 1.0f);
  bf16x8 o;
#pragma unroll
  for (int j = 0; j < 8; ++j) o[j] = f2bf((acc0[j] + acc1[j]) * inv);
  *reinterpret_cast<bf16x8*>(&A2[(size_t)node * 1024 + c]) = o;
}

// ---------------- bf16 MFMA GEMM core: 4-buffer stage-ahead-3 pipeline --------
// C[M,512] = A[M,K] @ B[512,K]^T + bias; optional RELU; coalesced bf16 store
// via padded LDS transpose staging.
template<int K, bool RELU>
__device__ __forceinline__ void gemm_body(
    const short* __restrict__ A, const short* __restrict__ B,
    const float* __restrict__ bias,
    short* __restrict__ outS, int ostride, int ooff, int nxp) {
  __shared__ short smem[32768];   // 64 KB: 4 x (A 4096 + B 4096 shorts)
  // XCD-bijective remap: all 4 col-blocks of a panel share lin%8 (same XCD L2)
  const int lin = blockIdx.x;
  const int pnl = (lin & 7) + ((lin >> 5) << 3);
  const int cbk = (lin >> 3) & 3;
  if (pnl >= nxp) return;
  const int m0 = pnl * 128, n0 = cbk * 128;
  const int t = threadIdx.x;
  const int l = t & 63, wid = t >> 6;
  const int wr = (wid >> 1) * 64, wc = (wid & 1) * 64;
  const int fr = l & 15, fs = l >> 4;

  f32x4 acc[4][4];
#pragma unroll
  for (int a = 0; a < 4; ++a)
#pragma unroll
    for (int b = 0; b < 4; ++b) acc[a][b] = (f32x4){0.f, 0.f, 0.f, 0.f};

  // staging geometry (swizzled source -> linear LDS; idx = r*4 + phys_slot)
  const int idx0 = t, r0 = idx0 >> 2, sp0 = idx0 & 3;
  const int sl0 = (sp0 - (r0 >> 1)) & 3;
  const int idx1 = t + 256, r1 = idx1 >> 2, sp1 = idx1 & 3;
  const int sl1 = (sp1 - (r1 >> 1)) & 3;
  int rowA0 = m0 + r0; rowA0 = rowA0 < N_NODES ? rowA0 : N_NODES - 1;
  int rowA1 = m0 + r1; rowA1 = rowA1 < N_NODES ? rowA1 : N_NODES - 1;
  const short* Ap0 = A + (size_t)rowA0 * K + sl0 * 8;
  const short* Ap1 = A + (size_t)rowA1 * K + sl1 * 8;
  const short* Bp0 = B + (size_t)(n0 + r0) * K + sl0 * 8;
  const short* Bp1 = B + (size_t)(n0 + r1) * K + sl1 * 8;

  constexpr int NK = K / 32;   // NK >= 4 required (192 -> 6, 1024 -> 32)

#define STAGE(bo, k0)                                  \
  gload16(Ap0 + (k0), &smem[(bo) + idx0 * 8]);         \
  gload16(Bp0 + (k0), &smem[(bo) + 4096 + idx0 * 8]);  \
  gload16(Ap1 + (k0), &smem[(bo) + idx1 * 8]);         \
  gload16(Bp1 + (k0), &smem[(bo) + 4096 + idx1 * 8]);

#define COMPUTE(bo) {                                                              \
  bf16x8 av[4], bv[4];                                                             \
  _Pragma("unroll")                                                                \
  for (int mi = 0; mi < 4; ++mi) {                                                 \
    const int r = wr + mi * 16 + fr;                                               \
    av[mi] = *reinterpret_cast<const bf16x8*>(                                     \
        &smem[(bo) + r * 32 + ((fs + (r >> 1)) & 3) * 8]);                         \
  }                                                                                \
  _Pragma("unroll")                                                                \
  for (int ni = 0; ni < 4; ++ni) {                                                 \
    const int r = wc + ni * 16 + fr;                                               \
    bv[ni] = *reinterpret_cast<const bf16x8*>(                                     \
        &smem[(bo) + 4096 + r * 32 + ((fs + (r >> 1)) & 3) * 8]);                  \
  }                                                                                \
  _Pragma("unroll")                                                                \
  for (int mi = 0; mi < 4; ++mi)                                                   \
    _Pragma("unroll")                                                              \
    for (int ni = 0; ni < 4; ++ni)                                                 \
      acc[mi][ni] = __builtin_amdgcn_mfma_f32_16x16x32_bf16(av[mi], bv[ni],        \
                                                            acc[mi][ni], 0, 0, 0); }

  // prologue: stage 0,1,2
  STAGE(0, 0)
  STAGE(8192, 32)
  STAGE(16384, 64)

#pragma unroll
  for (int k = 0; k < NK; ++k) {
    // wait own stage-k loads; keep stages k+1,k+2 in flight (4 loads each)
    if (k + 2 <= NK - 1)      { asm volatile("s_waitcnt vmcnt(8)" ::: "memory"); }
    else if (k + 1 <= NK - 1) { asm volatile("s_waitcnt vmcnt(4)" ::: "memory"); }
    else                      { asm volatile("s_waitcnt vmcnt(0)" ::: "memory"); }
    __builtin_amdgcn_s_barrier();
    if (k + 3 < NK) { STAGE(((k + 3) & 3) * 8192, (k + 3) * 32) }
    COMPUTE((k & 3) * 8192)
  }
#undef STAGE
#undef COMPUTE

  // ---- epilogue: stage C tile in LDS (stride 136 shorts, 16B-aligned rows),
  //      then fully-coalesced bf16x8 stores ----
  __syncthreads();
#pragma unroll
  for (int ni = 0; ni < 4; ++ni) {
    const int colL = wc + ni * 16 + fr;
    const float bb = bias[n0 + colL];
#pragma unroll
    for (int mi = 0; mi < 4; ++mi) {
      const f32x4 c = acc[mi][ni];
#pragma unroll
      for (int i = 0; i < 4; ++i) {
        const int rowL = wr + mi * 16 + fs * 4 + i;
        float v = c[i] + bb;
        if (RELU) v = fmaxf(v, 0.f);
        smem[rowL * 136 + colL] = f2bf(v);
      }
    }
  }
  __syncthreads();
  const int obase = ooff + n0;
#pragma unroll
  for (int pz = 0; pz < 8; ++pz) {
    const int idx = pz * 256 + t;
    const int row = idx >> 4, c8 = (idx & 15) << 3;
    if (m0 + row < N_NODES)
      *reinterpret_cast<bf16x8*>(&outS[(size_t)(m0 + row) * ostride + obase + c8]) =
          *reinterpret_cast<const bf16x8*>(&smem[row * 136 + c8]);
  }
}

__global__ __launch_bounds__(256) void k_gemm_l1(
    const short* __restrict__ A, const short* __restrict__ B,
    const float* __restrict__ bias, short* __restrict__ outS, int nxp) {
  gemm_body<192, true>(A, B, bias, outS, 1024, 512, nxp);
}
__global__ __launch_bounds__(256) void k_gemm_l2(
    const short* __restrict__ A, const short* __restrict__ B,
    const float* __restrict__ bias, short* __restrict__ outS, int nxp) {
  gemm_body<1024, false>(A, B, bias, outS, 512, 0, nxp);
}

// ---------------- pool: GR[g] = mean over rows of bf16 X2 --------------------
__global__ __launch_bounds__(256) void k_pool(const short* __restrict__ X2b,
                                              const int* __restrict__ rstart,
                                              float* __restrict__ GR) {
  __shared__ float part[4][HD];
  const int g = blockIdx.x, t = threadIdx.x;
  const int gi = t >> 6, l = t & 63;
  const int s0 = rstart[g], s1 = rstart[g + 1];
  float acc[8] = {0.f, 0.f, 0.f, 0.f, 0.f, 0.f, 0.f, 0.f};
  for (int r = s0 + gi; r < s1; r += 4) {
    bf16x8 v = *reinterpret_cast<const bf16x8*>(&X2b[(size_t)r * HD + l * 8]);
#pragma unroll
    for (int j = 0; j < 8; ++j) acc[j] += bf2f(v[j]);
  }
#pragma unroll
  for (int j = 0; j < 8; ++j) part[gi][l * 8 + j] = acc[j];
  __syncthreads();
  const float inv = 1.0f / fmaxf((float)(s1 - s0), 1.0f);
  for (int c = t; c < HD; c += 256)
    GR[g * HD + c] = (part[0][c] + part[1][c] + part[2][c] + part[3][c]) * inv;
}

// ---------------- classifier MLP1: h = relu(GR @ Wc1^T + bc1), bf16 weights ---
__global__ __launch_bounds__(256) void k_mlp1(
    const float* __restrict__ GR, const short* __restrict__ Wc1B,
    const float* __restrict__ bc1, float* __restrict__ HS) {
  __shared__ float grs[4][HD];
  const int g0 = blockIdx.x * 4, t = threadIdx.x;
  for (int f = t; f < 4 * HD / 4; f += 256) {
    int r = f >> 7, c = (f & 127) << 2;
    *reinterpret_cast<float4*>(&grs[r][c]) =
        *reinterpret_cast<const float4*>(&GR[(size_t)(g0 + r) * HD + c]);
  }
  __syncthreads();
  const int c = blockIdx.y * 256 + t;
  const short* wrow = &Wc1B[(size_t)c * HD];
  float a0 = 0.f, a1 = 0.f, a2 = 0.f, a3 = 0.f;
#pragma unroll 8
  for (int k8 = 0; k8 < HD / 8; ++k8) {
    bf16x8 w = *reinterpret_cast<const bf16x8*>(&wrow[k8 * 8]);
#pragma unroll
    for (int j = 0; j < 8; ++j) {
      const float wv = bf2f(w[j]);
      const int k = k8 * 8 + j;
      a0 = fmaf(wv, grs[0][k], a0);
      a1 = fmaf(wv, grs[1][k], a1);
      a2 = fmaf(wv, grs[2][k], a2);
      a3 = fmaf(wv, grs[3][k], a3);
    }
  }
  const float bb = bc1[c];
  HS[(size_t)(g0 + 0) * HD + c] = fmaxf(a0 + bb, 0.f);
  HS[(size_t)(g0 + 1) * HD + c] = fmaxf(a1 + bb, 0.f);
  HS[(size_t)(g0 + 2) * HD + c] = fmaxf(a2 + bb, 0.f);
  HS[(size_t)(g0 + 3) * HD + c] = fmaxf(a3 + bb, 0.f);
}

// ---------------- classifier MLP2: out = HS @ Wc2^T + bc2, bf16 weights ------
__global__ __launch_bounds__(256) void k_mlp2(
    const float* __restrict__ HS, const short* __restrict__ Wc2B,
    const float* __restrict__ bc2, float* __restrict__ out) {
  __shared__ float hsm[4][HD];
  const int g0 = blockIdx.x * 4, t = threadIdx.x;
  for (int f = t; f < 4 * HD / 4; f += 256) {
    int r = f >> 7, c = (f & 127) << 2;
    *reinterpret_cast<float4*>(&hsm[r][c]) =
        *reinterpret_cast<const float4*>(&HS[(size_t)(g0 + r) * HD + c]);
  }
  __syncthreads();
  const int c = blockIdx.y * 256 + t;
  if (c >= NTAC) return;
  const short* wrow = &Wc2B[(size_t)c * HD];
  float a0 = 0.f, a1 = 0.f, a2 = 0.f, a3 = 0.f;
#pragma unroll 8
  for (int k8 = 0; k8 < HD / 8; ++k8) {
    bf16x8 w = *reinterpret_cast<const bf16x8*>(&wrow[k8 * 8]);
#pragma unroll
    for (int j = 0; j < 8; ++j) {
      const float wv = bf2f(w[j]);
      const int k = k8 * 8 + j;
      a0 = fmaf(wv, hsm[0][k], a0);
      a1 = fmaf(wv, hsm[1][k], a1);
      a2 = fmaf(wv, hsm[2][k], a2);
      a3 = fmaf(wv, hsm[3][k], a3);
    }
  }
  const float bb = bc2[c];
  out[(size_t)(g0 + 0) * NTAC + c] = a0 + bb;
  out[(size_t)(g0 + 1) * NTAC + c] = a1 + bb;
  out[(size_t)(g0 + 2) * NTAC + c] = a2 + bb;
  out[(size_t)(g0 + 3) * NTAC + c] = a3 + bb;
}

extern "C" void kernel_launch(void* const* d_in, const int* in_sizes, int n_in,
                              void* d_out, int out_size, void* d_ws, size_t ws_size,
                              hipStream_t stream) {
  const int*   node_type = (const int*)d_in[0];
  const int*   node_tac  = (const int*)d_in[1];
  const int*   edge      = (const int*)d_in[2];
  const int*   batch     = (const int*)d_in[3];
  const float* temb      = (const float*)d_in[4];
  const float* tacemb    = (const float*)d_in[5];
  const float* W1l       = (const float*)d_in[6];
  const float* b1l       = (const float*)d_in[7];
  const float* W1r       = (const float*)d_in[8];
  const float* W2l       = (const float*)d_in[9];
  const float* b2l       = (const float*)d_in[10];
  const float* W2r       = (const float*)d_in[11];
  const float* Wc1       = (const float*)d_in[12];
  const float* bc1       = (const float*)d_in[13];
  const float* Wc2       = (const float*)d_in[14];
  const float* bc2       = (const float*)d_in[15];
  const int* src = edge;
  const int* dst = edge + N_EDGES;

  // ---- workspace layout ----
  char* p = (char*)d_ws;
  int*   DEG    = (int*)p;    p += N_NODES * 4;            // zeroed
  int*   CUR    = (int*)p;    p += N_NODES * 4;            // zeroed
  size_t zero_bytes = (size_t)(2 * N_NODES) * 4;
  int*   ROWS   = (int*)p;    p += (N_NODES + 4) * 4;
  int*   RSTART = (int*)p;    p += (NGRAPH + 4) * 4;
  int*   ESRC   = (int*)p;    p += N_EDGES * 4;
  short* A1     = (short*)p;  p += (size_t)N_NODES * 192 * 2;   // [agg1 | x]
  short* A2     = (short*)p;  p += (size_t)N_NODES * 1024 * 2;  // [agg2 | x1]
  short* X2B    = (short*)p;  p += (size_t)N_NODES * HD * 2;
  float* GR     = (float*)p;  p += NGRAPH * HD * 4;
  float* HS     = (float*)p;  p += NGRAPH * HD * 4;
  short* BC1    = (short*)p;  p += HD * 192 * 2;
  short* BC2    = (short*)p;  p += HD * 1024 * 2;
  short* WC1B   = (short*)p;  p += HD * HD * 2;
  short* WC2B   = (short*)p;  p += (size_t)NTAC * HD * 2;

  hipMemsetAsync(d_ws, 0, zero_bytes, stream);

  // fused prologue: weight casts + embedding + degree histogram + graph bounds
  const int front_items = HD * HD / 8 + NTAC * HD / 8 + HD * 192 / 8 +
                          HD * 1024 / 8 + N_NODES * 24 + N_EDGES + N_NODES;
  k_front<<<(front_items + 255) / 256, 256, 0, stream>>>(
      Wc1, Wc2, WC1B, WC2B, W1l, W1r, BC1, W2l, W2r, BC2,
      node_type, node_tac, temb, tacemb, A1, dst, DEG, batch, RSTART);

  k_scan<<<1, 1024, 0, stream>>>(DEG, ROWS);
  k_scatter<<<N_EDGES / 256, 256, 0, stream>>>(src, dst, ROWS, CUR, ESRC);

  k_gather96<<<(N_NODES * 24) / 256, 256, 0, stream>>>(ROWS, ESRC, A1);
  const int NXP = (N_NODES + 127) / 128;          // 157 row panels
  const int GEMM_BLOCKS = 640;                    // 160 panels x 4, bijective swizzle
  k_gemm_l1<<<GEMM_BLOCKS, 256, 0, stream>>>(A1, BC1, b1l, A2, NXP);
  k_gather512<<<(N_NODES * 64) / 256, 256, 0, stream>>>(ROWS, ESRC, A2);
  k_gemm_l2<<<GEMM_BLOCKS, 256, 0, stream>>>(A2, BC2, b2l, X2B, NXP);
  k_pool<<<NGRAPH, 256, 0, stream>>>(X2B, RSTART, GR);
  k_mlp1<<<dim3(NGRAPH / 4, 2), 256, 0, stream>>>(GR, WC1B, bc1, HS);
  k_mlp2<<<dim3(NGRAPH / 4, 4), 256, 0, stream>>>(HS, WC2B, bc2, (float*)d_out);
}